// Round 6
// baseline (573.327 us; speedup 1.0000x reference)
//
#include <hip/hip_runtime.h>
#include <hip/hip_bf16.h>

// MambaTower: B=1, L=2048, DM=256, E=512, N=16, R=16, K=4, NL=4, CA at layers 1,3
// fp32 tensors; GEMMs via bf16 MFMA (BK=128); dt_proj folded into x_proj;
// rmsnorm + combine folded into GEMM A-staging. Scan: 16 states in registers.

constexpr int L_ = 2048, DM_ = 256, E_ = 512;
constexpr int CH = 64, CL = 32;  // scan chunks x chunk length (CH*CL == L_)

typedef __attribute__((ext_vector_type(8))) short bf16x8;
typedef __attribute__((ext_vector_type(4))) float f32x4;

__device__ __forceinline__ float siluf(float x) { return x / (1.f + __expf(-x)); }
__device__ __forceinline__ unsigned short f2b(float f) {
  union { float f; unsigned u; } x; x.f = f;
  unsigned r = x.u + 0x7fff + ((x.u >> 16) & 1);
  return (unsigned short)(r >> 16);
}

// ---------------- row rms scale only: rn[row] = rsqrt(mean(x^2)+eps) ----------------
__global__ __launch_bounds__(256) void rnorm_k(const float* __restrict__ X,
                                               float* __restrict__ rn) {
  int lane = threadIdx.x & 63, wv = threadIdx.x >> 6;
  int row = blockIdx.x * 4 + wv;
  const float4 xv = *(const float4*)(X + (size_t)row * DM_ + lane * 4);
  float ss = xv.x * xv.x + xv.y * xv.y + xv.z * xv.z + xv.w * xv.w;
  #pragma unroll
  for (int off = 1; off < 64; off <<= 1) ss += __shfl_xor(ss, off);
  if (lane == 0) rn[row] = rsqrtf(ss * (1.f / DM_) + 1e-6f);
}

// ---------------- weight prep: transpose+cast fp32 [K][N] -> bf16 [N][K] ----------------
__global__ __launch_bounds__(256) void tcast_k(const float* __restrict__ in,
                                               unsigned short* __restrict__ out,
                                               int K, int N) {
  in  += (size_t)blockIdx.z * K * N;
  out += (size_t)blockIdx.z * K * N;
  __shared__ float t[32][33];
  int n0 = blockIdx.x * 32, k0 = blockIdx.y * 32;
  int tx = threadIdx.x & 31, ty = threadIdx.x >> 5;
  #pragma unroll
  for (int i = 0; i < 32; i += 8)
    t[ty + i][tx] = in[(size_t)(k0 + ty + i) * N + n0 + tx];
  __syncthreads();
  #pragma unroll
  for (int i = 0; i < 32; i += 8)
    out[(size_t)(n0 + ty + i) * K + k0 + tx] = f2b(t[tx][ty + i]);
}

// ---------------- weight prep: WXT[layer] = [Wdt^T | xwBC^T | 0pad] bf16 [576][512] ----------
__global__ void wdt_k(const float* __restrict__ xpw, const float* __restrict__ dpw,
                      unsigned short* __restrict__ WXT) {
  int l = blockIdx.y;
  const float* xw = xpw + (size_t)l * 512 * 48;
  const float* dw = dpw + (size_t)l * 16 * 512;
  unsigned short* out = WXT + (size_t)l * 576 * 512;
  int b = blockIdx.x, t = threadIdx.x;
  if (b < 1024) {
    int idx = b * 256 + t;
    int k = idx & 511, n = idx >> 9;
    float s = 0.f;
    #pragma unroll
    for (int r = 0; r < 16; ++r) s = fmaf(xw[k * 48 + r], dw[r * 512 + n], s);
    out[(size_t)n * 512 + k] = f2b(s);
  } else if (b < 1088) {
    int idx = (b - 1024) * 256 + t;
    int k = idx & 511, j = idx >> 9;
    out[(size_t)(512 + j) * 512 + k] = f2b(xw[k * 48 + 16 + j]);
  } else {
    int idx = (b - 1088) * 256 + t;
    int k = idx & 511, j = idx >> 9;
    out[(size_t)(544 + j) * 512 + k] = 0;
  }
}

// ---------------- MFMA GEMM: C[2048 x N] = op(srcA * BT^T), BK=128 ----------------
// AMODE: 0 plain A[row*lda+k] | 1 rmsnorm: X[row*lda+k]*rn[row]*w[k] (Aux1=rn, Aux2=w)
//        2 combine: (Y2f[row*512+k]+Y2b[(2047-row)*512+k])*silu(Z[row*1024+k]), Aux1=XZ+512
// MODE:  0 store | 1 softplus(v+bias) for gn<512 else store | 2 C+=v | 3 store v+bias | 4 C+=v+bias
template<int AMODE, int MODE>
__global__ __launch_bounds__(256) void mgemm_k(
    const float* __restrict__ A, int lda, size_t saz,
    const float* __restrict__ Aux1, const float* __restrict__ Aux2,
    const unsigned short* __restrict__ BT,
    const float* __restrict__ bias,
    float* __restrict__ C, int ldc, size_t scz,
    int Kd) {
  A += (size_t)blockIdx.z * saz;
  C += (size_t)blockIdx.z * scz;
  __shared__ unsigned short Als[64 * 128];
  __shared__ unsigned short Bls[64 * 128];
  const int tid = threadIdx.x;
  const int lane = tid & 63, wave = tid >> 6;
  const int wm = wave >> 1, wn = wave & 1;
  const int m0 = blockIdx.y * 64, n0 = blockIdx.x * 64;
  const int srow = tid >> 2, sc = tid & 3;
  const unsigned swz = (unsigned)((srow & 7) << 4);
  const int arow = m0 + srow;
  float rnv = (AMODE == 1) ? Aux1[arow] : 0.f;
  f32x4 acc[2][2] = {};
  for (int k0 = 0; k0 < Kd; k0 += 128) {
    __syncthreads();
    // stage A: 32 fp32 -> bf16 per thread
    #pragma unroll
    for (int i = 0; i < 8; ++i) {
      int k = sc * 32 + i * 4;
      float4 v;
      if (AMODE == 2) {
        float4 yf = *(const float4*)(A + (size_t)arow * 512 + k0 + k);
        float4 yb = *(const float4*)(A + (size_t)L_ * E_ + (size_t)(2047 - arow) * 512 + k0 + k);
        float4 z  = *(const float4*)(Aux1 + (size_t)arow * 1024 + k0 + k);
        v.x = (yf.x + yb.x) * siluf(z.x);
        v.y = (yf.y + yb.y) * siluf(z.y);
        v.z = (yf.z + yb.z) * siluf(z.z);
        v.w = (yf.w + yb.w) * siluf(z.w);
      } else {
        v = *(const float4*)(A + (size_t)arow * lda + k0 + k);
        if (AMODE == 1) {
          float4 w4 = *(const float4*)(Aux2 + k0 + k);
          v.x *= rnv * w4.x; v.y *= rnv * w4.y; v.z *= rnv * w4.z; v.w *= rnv * w4.w;
        }
      }
      uint2 p;
      p.x = (unsigned)f2b(v.x) | ((unsigned)f2b(v.y) << 16);
      p.y = (unsigned)f2b(v.z) | ((unsigned)f2b(v.w) << 16);
      unsigned off = (unsigned)(srow * 256 + k * 2) ^ swz;
      *(uint2*)((char*)Als + off) = p;
    }
    // stage B: 32 bf16 per thread
    #pragma unroll
    for (int i = 0; i < 4; ++i) {
      int k = sc * 32 + i * 8;
      uint4 v = *(const uint4*)(BT + (size_t)(n0 + srow) * Kd + k0 + k);
      unsigned off = (unsigned)(srow * 256 + k * 2) ^ swz;
      *(uint4*)((char*)Bls + off) = v;
    }
    __syncthreads();
    #pragma unroll
    for (int ks = 0; ks < 128; ks += 32) {
      bf16x8 af[2], bfr[2];
      #pragma unroll
      for (int mi = 0; mi < 2; ++mi) {
        int row = wm * 32 + mi * 16 + (lane & 15);
        unsigned off = (unsigned)(row * 256 + (ks + (lane >> 4) * 8) * 2) ^ ((unsigned)((row & 7) << 4));
        af[mi] = *(const bf16x8*)((const char*)Als + off);
      }
      #pragma unroll
      for (int ni = 0; ni < 2; ++ni) {
        int row = wn * 32 + ni * 16 + (lane & 15);
        unsigned off = (unsigned)(row * 256 + (ks + (lane >> 4) * 8) * 2) ^ ((unsigned)((row & 7) << 4));
        bfr[ni] = *(const bf16x8*)((const char*)Bls + off);
      }
      #pragma unroll
      for (int mi = 0; mi < 2; ++mi)
        #pragma unroll
        for (int ni = 0; ni < 2; ++ni)
          acc[mi][ni] = __builtin_amdgcn_mfma_f32_16x16x32_bf16(af[mi], bfr[ni], acc[mi][ni], 0, 0, 0);
    }
  }
  #pragma unroll
  for (int mi = 0; mi < 2; ++mi) {
    #pragma unroll
    for (int ni = 0; ni < 2; ++ni) {
      int gm = m0 + wm * 32 + mi * 16 + (lane >> 4) * 4;
      int gn = n0 + wn * 32 + ni * 16 + (lane & 15);
      float bv = (MODE == 3 || MODE == 4) ? bias[gn] : 0.f;
      #pragma unroll
      for (int r = 0; r < 4; ++r) {
        float x = acc[mi][ni][r];
        if (MODE == 1) {
          if (gn < 512) {
            x += bias[gn];
            x = (x > 20.f) ? x : log1pf(__expf(x));
          }
        }
        if (MODE == 3 || MODE == 4) x += bv;
        float* cp = C + (size_t)(gm + r) * ldc + gn;
        if (MODE == 2 || MODE == 4) *cp += x; else *cp = x;
      }
    }
  }
}

// ---------------- depthwise causal conv (both directions) + silu ----------------
__global__ void conv_k(const float* __restrict__ XZ, const float* __restrict__ cw,
                       const float* __restrict__ cb, float* __restrict__ UC) {
  int idx = blockIdx.x * 256 + threadIdx.x;
  if (idx >= L_ * E_) return;
  int e = idx & (E_ - 1);
  int l = idx >> 9;
  float w0 = cw[0 * E_ + e], w1 = cw[1 * E_ + e];
  float w2 = cw[2 * E_ + e], w3 = cw[3 * E_ + e];
  float b = cb[e];
  float af = b, ab = b;
  #pragma unroll
  for (int k = 0; k < 4; ++k) {
    int j = l - 3 + k;
    if (j >= 0) {
      float wk = (k == 0) ? w0 : (k == 1) ? w1 : (k == 2) ? w2 : w3;
      af += wk * XZ[(size_t)j * 1024 + e];
      ab += wk * XZ[(size_t)(L_ - 1 - j) * 1024 + e];
    }
  }
  UC[idx] = siluf(af);
  UC[L_ * E_ + idx] = siluf(ab);
}

// ---------------- selective scan: thread=(dir,e), 16 states in regs ----------------
__global__ __launch_bounds__(256) void scan1_k(
    const float* __restrict__ PRDb, const float* __restrict__ UCb,
    const float* __restrict__ alog, float* __restrict__ SP, float* __restrict__ SH) {
  int b = blockIdx.x;
  int eg = b & 1, chunk = (b >> 1) & (CH - 1), dir = b >> 7;
  int e = eg * 256 + threadIdx.x;
  int l0 = chunk * CL;
  const float* prd = PRDb + (size_t)dir * L_ * 576;
  const float* ucp = UCb + (size_t)dir * L_ * E_;
  __shared__ float B_s[CL][16];
  for (int i = threadIdx.x; i < CL * 16; i += 256) {
    int l = i >> 4, n = i & 15;
    B_s[l][n] = prd[(size_t)(l0 + l) * 576 + 512 + n];
  }
  float A[16];
  #pragma unroll
  for (int n = 0; n < 16; n += 4) {
    float4 v = *(const float4*)&alog[(size_t)e * 16 + n];
    A[n] = -__expf(v.x); A[n+1] = -__expf(v.y); A[n+2] = -__expf(v.z); A[n+3] = -__expf(v.w);
  }
  float h[16];
  #pragma unroll
  for (int n = 0; n < 16; ++n) h[n] = 0.f;
  float sd = 0.f;
  __syncthreads();
  #pragma unroll
  for (int t = 0; t < CL; t += 8) {
    float d[8], u[8];
    #pragma unroll
    for (int j = 0; j < 8; ++j) {
      d[j] = prd[(size_t)(l0 + t + j) * 576 + e];
      u[j] = ucp[(size_t)(l0 + t + j) * E_ + e];
    }
    #pragma unroll
    for (int j = 0; j < 8; ++j) {
      float du = d[j] * u[j];
      sd += d[j];
      #pragma unroll
      for (int n = 0; n < 16; ++n)
        h[n] = fmaf(__expf(d[j] * A[n]), h[n], du * B_s[t + j][n]);
    }
  }
  size_t idx = ((size_t)(dir * CH + chunk) * 8192) + (size_t)e * 16;
  #pragma unroll
  for (int n = 0; n < 16; ++n) {
    SP[idx + n] = __expf(A[n] * sd);
    SH[idx + n] = h[n];
  }
}

__global__ void scan2_k(float* __restrict__ SP, const float* __restrict__ SH) {
  int idx = blockIdx.x * 256 + threadIdx.x;  // 2*8192
  if (idx >= 2 * E_ * 16) return;
  int dir = idx >> 13, en = idx & 8191;
  float c = 0.f;
  #pragma unroll
  for (int j = 0; j < CH; ++j) {
    size_t s = (size_t)(dir * CH + j) * 8192 + en;
    float p = SP[s], hh = SH[s];
    SP[s] = c;
    c = p * c + hh;
  }
}

__global__ __launch_bounds__(256) void scan3_k(
    const float* __restrict__ PRDb, const float* __restrict__ UCb,
    const float* __restrict__ alog, const float* __restrict__ dp,
    const float* __restrict__ CIN, float* __restrict__ Y2) {
  int b = blockIdx.x;
  int eg = b & 1, chunk = (b >> 1) & (CH - 1), dir = b >> 7;
  int e = eg * 256 + threadIdx.x;
  int l0 = chunk * CL;
  const float* prd = PRDb + (size_t)dir * L_ * 576;
  const float* ucp = UCb + (size_t)dir * L_ * E_;
  float* Y = Y2 + (size_t)dir * L_ * E_;
  __shared__ float B_s[CL][16], C_s[CL][16];
  for (int i = threadIdx.x; i < CL * 16; i += 256) {
    int l = i >> 4, n = i & 15;
    B_s[l][n] = prd[(size_t)(l0 + l) * 576 + 512 + n];
    C_s[l][n] = prd[(size_t)(l0 + l) * 576 + 528 + n];
  }
  float A[16];
  #pragma unroll
  for (int n = 0; n < 16; n += 4) {
    float4 v = *(const float4*)&alog[(size_t)e * 16 + n];
    A[n] = -__expf(v.x); A[n+1] = -__expf(v.y); A[n+2] = -__expf(v.z); A[n+3] = -__expf(v.w);
  }
  float D = dp[e];
  float h[16];
  {
    size_t idx = ((size_t)(dir * CH + chunk) * 8192) + (size_t)e * 16;
    #pragma unroll
    for (int n = 0; n < 16; n += 4) {
      float4 v = *(const float4*)&CIN[idx + n];
      h[n] = v.x; h[n+1] = v.y; h[n+2] = v.z; h[n+3] = v.w;
    }
  }
  __syncthreads();
  #pragma unroll
  for (int t = 0; t < CL; t += 8) {
    float d[8], u[8];
    #pragma unroll
    for (int j = 0; j < 8; ++j) {
      d[j] = prd[(size_t)(l0 + t + j) * 576 + e];
      u[j] = ucp[(size_t)(l0 + t + j) * E_ + e];
    }
    #pragma unroll
    for (int j = 0; j < 8; ++j) {
      float du = d[j] * u[j];
      float y0 = 0.f, y1 = 0.f, y2 = 0.f, y3 = 0.f;
      #pragma unroll
      for (int n = 0; n < 16; n += 4) {
        h[n]   = fmaf(__expf(d[j] * A[n]),   h[n],   du * B_s[t + j][n]);
        h[n+1] = fmaf(__expf(d[j] * A[n+1]), h[n+1], du * B_s[t + j][n+1]);
        h[n+2] = fmaf(__expf(d[j] * A[n+2]), h[n+2], du * B_s[t + j][n+2]);
        h[n+3] = fmaf(__expf(d[j] * A[n+3]), h[n+3], du * B_s[t + j][n+3]);
        y0 = fmaf(h[n],   C_s[t + j][n],   y0);
        y1 = fmaf(h[n+1], C_s[t + j][n+1], y1);
        y2 = fmaf(h[n+2], C_s[t + j][n+2], y2);
        y3 = fmaf(h[n+3], C_s[t + j][n+3], y3);
      }
      Y[(size_t)(l0 + t + j) * E_ + e] = (y0 + y1) + (y2 + y3) + u[j] * D;
    }
  }
}

// ---------------- cross-attention core ----------------
__global__ __launch_bounds__(256) void attn_k(
    const float* __restrict__ Q, const float* __restrict__ te,
    const float* __restrict__ kw, const float* __restrict__ vw, const float* __restrict__ vb,
    float* __restrict__ AO) {
  int lane = threadIdx.x & 63, h = threadIdx.x >> 6;
  int l0 = blockIdx.x * 8;
  const float* kp0 = kw + (size_t)lane * DM_ + h * 64;
  const float* vp0 = vw + h * 64 + lane;
  float vbv = vb[h * 64 + lane];
  for (int p = 0; p < 8; ++p) {
    int l = l0 + p;
    float q = Q[(size_t)l * DM_ + h * 64 + lane];
    float g = 0.f;
    #pragma unroll
    for (int d0 = 0; d0 < 64; d0 += 4) {
      float4 r = *(const float4*)(kp0 + d0);
      g = fmaf(r.x, __shfl(q, d0 + 0), g);
      g = fmaf(r.y, __shfl(q, d0 + 1), g);
      g = fmaf(r.z, __shfl(q, d0 + 2), g);
      g = fmaf(r.w, __shfl(q, d0 + 3), g);
    }
    float tfv[8], pv[8];
    #pragma unroll
    for (int t = 0; t < 8; ++t) {
      tfv[t] = te[(size_t)t * L_ * 64 + (size_t)l * 64 + lane];
      pv[t] = tfv[t] * g;
    }
    #pragma unroll
    for (int t = 0; t < 8; ++t) {
      #pragma unroll
      for (int off = 1; off < 64; off <<= 1) pv[t] += __shfl_xor(pv[t], off);
    }
    float mx = pv[0];
    #pragma unroll
    for (int t = 1; t < 8; ++t) mx = fmaxf(mx, pv[t]);
    float s = 0.f;
    #pragma unroll
    for (int t = 0; t < 8; ++t) { pv[t] = __expf((pv[t] - mx) * 0.125f); s += pv[t]; }
    float inv = 1.f / s;
    float m = 0.f;
    #pragma unroll
    for (int t = 0; t < 8; ++t) m = fmaf(pv[t] * inv, tfv[t], m);
    float o = vbv;
    #pragma unroll 8
    for (int c = 0; c < 64; ++c)
      o = fmaf(__shfl(m, c), vp0[(size_t)c * DM_], o);
    AO[(size_t)l * DM_ + h * 64 + lane] = o;
  }
}

extern "C" void kernel_launch(void* const* d_in, const int* in_sizes, int n_in,
                              void* d_out, int out_size, void* d_ws, size_t ws_size,
                              hipStream_t stream) {
  (void)in_sizes; (void)n_in; (void)out_size; (void)ws_size;
  const float* x_in = (const float*)d_in[0];
  const float* te   = (const float*)d_in[1];
  const float* mnw  = (const float*)d_in[2];
  const float* ipw  = (const float*)d_in[3];
  const float* cw   = (const float*)d_in[4];
  const float* cb   = (const float*)d_in[5];
  const float* xpw  = (const float*)d_in[6];
  const float* dpw  = (const float*)d_in[7];
  const float* dpb  = (const float*)d_in[8];
  const float* alog = (const float*)d_in[9];
  const float* dprm = (const float*)d_in[10];
  const float* opw  = (const float*)d_in[11];
  const float* cnw  = (const float*)d_in[12];
  const float* qw   = (const float*)d_in[13];
  const float* qb   = (const float*)d_in[14];
  const float* kw   = (const float*)d_in[15];
  // d_in[16] = k_b: constant over tracks -> softmax-invariant, unused
  const float* vw   = (const float*)d_in[17];
  const float* vb   = (const float*)d_in[18];
  const float* ow   = (const float*)d_in[19];
  const float* ob   = (const float*)d_in[20];

  float* ws = (float*)d_ws;
  float* X   = ws + 0;          // 524288
  float* XZ  = ws + 524288;     // 2097152
  float* UC  = ws + 2621440;    // 2097152 (dir0, dir1)
  float* PRD = ws + 4718592;    // 2359296 = 2 x 2048 x 576
  float* Y2  = ws + 7077888;    // 2097152
  float* SP  = ws + 9175040;    // 1048576
  float* SH  = ws + 10223616;   // 1048576
  unsigned short* ipwT = (unsigned short*)(ws + 11272192);  // 524288 fl
  unsigned short* WXT  = (unsigned short*)(ws + 11796480);  // 589824 fl
  unsigned short* opwT = (unsigned short*)(ws + 12386304);  // 262144 fl
  unsigned short* qwT  = (unsigned short*)(ws + 12648448);  // 65536 fl
  unsigned short* owT  = (unsigned short*)(ws + 12713984);  // 65536 fl
  float* RN = ws + 12779520;    // 2048 (16B-aligned)
  // end: 12781568 floats = 51.1 MB
  float* Qb = SP;  // alias SP (dead in CA phase)
  float* AO = SH;  // alias SH (dead in CA phase)

  tcast_k<<<dim3(32, 8, 4), 256, 0, stream>>>(ipw, ipwT, 256, 1024);
  tcast_k<<<dim3(8, 16, 4), 256, 0, stream>>>(opw, opwT, 512, 256);
  tcast_k<<<dim3(8, 8, 2), 256, 0, stream>>>(qw, qwT, 256, 256);
  tcast_k<<<dim3(8, 8, 2), 256, 0, stream>>>(ow, owT, 256, 256);
  wdt_k<<<dim3(1152, 4), 256, 0, stream>>>(xpw, dpw, WXT);

  hipMemcpyAsync(X, x_in, (size_t)L_ * DM_ * sizeof(float),
                 hipMemcpyDeviceToDevice, stream);

  for (int i = 0; i < 4; ++i) {
    rnorm_k<<<512, 256, 0, stream>>>(X, RN);
    mgemm_k<1,0><<<dim3(16, 32, 1), 256, 0, stream>>>(
        X, 256, 0, RN, mnw + i * 256, ipwT + (size_t)i * 1024 * 256, nullptr,
        XZ, 1024, 0, 256);
    conv_k<<<4096, 256, 0, stream>>>(XZ, cw + i * 4 * 512, cb + i * 512, UC);
    mgemm_k<0,1><<<dim3(9, 32, 2), 256, 0, stream>>>(
        UC, 512, 1048576, nullptr, nullptr, WXT + (size_t)i * 576 * 512, dpb + i * 512,
        PRD, 576, 1179648, 512);
    scan1_k<<<2 * CH * 2, 256, 0, stream>>>(PRD, UC, alog + (size_t)i * 512 * 16, SP, SH);
    scan2_k<<<64, 256, 0, stream>>>(SP, SH);
    scan3_k<<<2 * CH * 2, 256, 0, stream>>>(PRD, UC, alog + (size_t)i * 512 * 16,
                                            dprm + i * 512, SP, Y2);
    mgemm_k<2,2><<<dim3(4, 32, 1), 256, 0, stream>>>(
        Y2, 512, 0, XZ + 512, nullptr, opwT + (size_t)i * 256 * 512, nullptr,
        X, 256, 0, 512);

    if (i == 1 || i == 3) {
      int j = (i == 1) ? 0 : 1;
      rnorm_k<<<512, 256, 0, stream>>>(X, RN);
      mgemm_k<1,3><<<dim3(4, 32, 1), 256, 0, stream>>>(
          X, 256, 0, RN, cnw + j * 256, qwT + (size_t)j * 256 * 256, qb + j * 256,
          Qb, 256, 0, 256);
      attn_k<<<256, 256, 0, stream>>>(Qb, te, kw + (size_t)j * 64 * 256,
                                      vw + (size_t)j * 64 * 256, vb + j * 256, AO);
      mgemm_k<0,4><<<dim3(4, 32, 1), 256, 0, stream>>>(
          AO, 256, 0, nullptr, nullptr, owT + (size_t)j * 256 * 256, ob + j * 256,
          X, 256, 0, 256);
    }
  }

  hipMemcpyAsync(d_out, X, (size_t)L_ * DM_ * sizeof(float),
                 hipMemcpyDeviceToDevice, stream);
}

// Round 7
// 532.269 us; speedup vs baseline: 1.0771x; 1.0771x over previous
//
#include <hip/hip_runtime.h>
#include <hip/hip_bf16.h>

// MambaTower: B=1, L=2048, DM=256, E=512, N=16, R=16, K=4, NL=4, CA at layers 1,3
// fp32 tensors; GEMMs via bf16 MFMA (BK=64 — BK=128 measured -68us regression R6);
// dt_proj folded into x_proj; rmsnorm + combine folded into GEMM A-staging.
// Scan: thread=(dir,e), 16 states in registers.

constexpr int L_ = 2048, DM_ = 256, E_ = 512;
constexpr int CH = 64, CL = 32;  // scan chunks x chunk length (CH*CL == L_)

typedef __attribute__((ext_vector_type(8))) short bf16x8;
typedef __attribute__((ext_vector_type(4))) float f32x4;

__device__ __forceinline__ float siluf(float x) { return x / (1.f + __expf(-x)); }
__device__ __forceinline__ unsigned short f2b(float f) {
  union { float f; unsigned u; } x; x.f = f;
  unsigned r = x.u + 0x7fff + ((x.u >> 16) & 1);
  return (unsigned short)(r >> 16);
}

// ---------------- row rms scale only: rn[row] = rsqrt(mean(x^2)+eps) ----------------
__global__ __launch_bounds__(256) void rnorm_k(const float* __restrict__ X,
                                               float* __restrict__ rn) {
  int lane = threadIdx.x & 63, wv = threadIdx.x >> 6;
  int row = blockIdx.x * 4 + wv;
  const float4 xv = *(const float4*)(X + (size_t)row * DM_ + lane * 4);
  float ss = xv.x * xv.x + xv.y * xv.y + xv.z * xv.z + xv.w * xv.w;
  #pragma unroll
  for (int off = 1; off < 64; off <<= 1) ss += __shfl_xor(ss, off);
  if (lane == 0) rn[row] = rsqrtf(ss * (1.f / DM_) + 1e-6f);
}

// ---------------- weight prep: transpose+cast fp32 [K][N] -> bf16 [N][K] ----------------
__global__ __launch_bounds__(256) void tcast_k(const float* __restrict__ in,
                                               unsigned short* __restrict__ out,
                                               int K, int N) {
  in  += (size_t)blockIdx.z * K * N;
  out += (size_t)blockIdx.z * K * N;
  __shared__ float t[32][33];
  int n0 = blockIdx.x * 32, k0 = blockIdx.y * 32;
  int tx = threadIdx.x & 31, ty = threadIdx.x >> 5;
  #pragma unroll
  for (int i = 0; i < 32; i += 8)
    t[ty + i][tx] = in[(size_t)(k0 + ty + i) * N + n0 + tx];
  __syncthreads();
  #pragma unroll
  for (int i = 0; i < 32; i += 8)
    out[(size_t)(n0 + ty + i) * K + k0 + tx] = f2b(t[tx][ty + i]);
}

// ---------------- weight prep: WXT[layer] = [Wdt^T | xwBC^T | 0pad] bf16 [576][512] ----------
__global__ void wdt_k(const float* __restrict__ xpw, const float* __restrict__ dpw,
                      unsigned short* __restrict__ WXT) {
  int l = blockIdx.y;
  const float* xw = xpw + (size_t)l * 512 * 48;
  const float* dw = dpw + (size_t)l * 16 * 512;
  unsigned short* out = WXT + (size_t)l * 576 * 512;
  int b = blockIdx.x, t = threadIdx.x;
  if (b < 1024) {
    int idx = b * 256 + t;
    int k = idx & 511, n = idx >> 9;
    float s = 0.f;
    #pragma unroll
    for (int r = 0; r < 16; ++r) s = fmaf(xw[k * 48 + r], dw[r * 512 + n], s);
    out[(size_t)n * 512 + k] = f2b(s);
  } else if (b < 1088) {
    int idx = (b - 1024) * 256 + t;
    int k = idx & 511, j = idx >> 9;
    out[(size_t)(512 + j) * 512 + k] = f2b(xw[k * 48 + 16 + j]);
  } else {
    int idx = (b - 1088) * 256 + t;
    int k = idx & 511, j = idx >> 9;
    out[(size_t)(544 + j) * 512 + k] = 0;
  }
}

// ---------------- MFMA GEMM: C[2048 x N] = op(srcA * BT^T), BK=64 ----------------
// AMODE: 0 plain A[row*lda+k] | 1 rmsnorm: X[row*lda+k]*rn[row]*w[k] (Aux1=rn, Aux2=w)
//        2 combine: (Y2f[row*512+k]+Y2b[(2047-row)*512+k])*silu(Z[row*1024+k]), Aux1=XZ+512
// MODE:  0 store | 1 softplus(v+bias) for gn<512 else store | 2 C+=v | 3 store v+bias | 4 C+=v+bias
template<int AMODE, int MODE>
__global__ __launch_bounds__(256) void mgemm_k(
    const float* __restrict__ A, int lda, size_t saz,
    const float* __restrict__ Aux1, const float* __restrict__ Aux2,
    const unsigned short* __restrict__ BT,
    const float* __restrict__ bias,
    float* __restrict__ C, int ldc, size_t scz,
    int Kd) {
  A += (size_t)blockIdx.z * saz;
  C += (size_t)blockIdx.z * scz;
  __shared__ unsigned short Als[64 * 64];
  __shared__ unsigned short Bls[64 * 64];
  const int tid = threadIdx.x;
  const int lane = tid & 63, wave = tid >> 6;
  const int wm = wave >> 1, wn = wave & 1;
  const int m0 = blockIdx.y * 64, n0 = blockIdx.x * 64;
  const int srow = tid >> 2, sc = tid & 3;
  const unsigned swz = (unsigned)((srow & 7) << 4);
  const int arow = m0 + srow;
  float rnv = (AMODE == 1) ? Aux1[arow] : 0.f;
  f32x4 acc[2][2] = {};
  for (int k0 = 0; k0 < Kd; k0 += 64) {
    __syncthreads();
    // stage A: 16 fp32 -> bf16 per thread
    #pragma unroll
    for (int i = 0; i < 4; ++i) {
      int k = sc * 16 + i * 4;
      float4 v;
      if (AMODE == 2) {
        float4 yf = *(const float4*)(A + (size_t)arow * 512 + k0 + k);
        float4 yb = *(const float4*)(A + (size_t)L_ * E_ + (size_t)(2047 - arow) * 512 + k0 + k);
        float4 z  = *(const float4*)(Aux1 + (size_t)arow * 1024 + k0 + k);
        v.x = (yf.x + yb.x) * siluf(z.x);
        v.y = (yf.y + yb.y) * siluf(z.y);
        v.z = (yf.z + yb.z) * siluf(z.z);
        v.w = (yf.w + yb.w) * siluf(z.w);
      } else {
        v = *(const float4*)(A + (size_t)arow * lda + k0 + k);
        if (AMODE == 1) {
          float4 w4 = *(const float4*)(Aux2 + k0 + k);
          v.x *= rnv * w4.x; v.y *= rnv * w4.y; v.z *= rnv * w4.z; v.w *= rnv * w4.w;
        }
      }
      uint2 p;
      p.x = (unsigned)f2b(v.x) | ((unsigned)f2b(v.y) << 16);
      p.y = (unsigned)f2b(v.z) | ((unsigned)f2b(v.w) << 16);
      unsigned off = (unsigned)(srow * 128 + k * 2) ^ swz;
      *(uint2*)((char*)Als + off) = p;
    }
    // stage B: 16 bf16 per thread (2 x 16B)
    {
      const unsigned short* bp = BT + (size_t)(n0 + srow) * Kd + k0 + sc * 8;
      #pragma unroll
      for (int i = 0; i < 2; ++i) {
        uint4 v = *(const uint4*)(bp + i * 32);
        unsigned off = (unsigned)(srow * 128 + (sc * 8 + i * 32) * 2) ^ swz;
        *(uint4*)((char*)Bls + off) = v;
      }
    }
    __syncthreads();
    #pragma unroll
    for (int ks = 0; ks < 64; ks += 32) {
      bf16x8 af[2], bfr[2];
      #pragma unroll
      for (int mi = 0; mi < 2; ++mi) {
        int row = wm * 32 + mi * 16 + (lane & 15);
        unsigned off = (unsigned)(row * 128 + (ks + (lane >> 4) * 8) * 2) ^ ((unsigned)((row & 7) << 4));
        af[mi] = *(const bf16x8*)((const char*)Als + off);
      }
      #pragma unroll
      for (int ni = 0; ni < 2; ++ni) {
        int row = wn * 32 + ni * 16 + (lane & 15);
        unsigned off = (unsigned)(row * 128 + (ks + (lane >> 4) * 8) * 2) ^ ((unsigned)((row & 7) << 4));
        bfr[ni] = *(const bf16x8*)((const char*)Bls + off);
      }
      #pragma unroll
      for (int mi = 0; mi < 2; ++mi)
        #pragma unroll
        for (int ni = 0; ni < 2; ++ni)
          acc[mi][ni] = __builtin_amdgcn_mfma_f32_16x16x32_bf16(af[mi], bfr[ni], acc[mi][ni], 0, 0, 0);
    }
  }
  #pragma unroll
  for (int mi = 0; mi < 2; ++mi) {
    #pragma unroll
    for (int ni = 0; ni < 2; ++ni) {
      int gm = m0 + wm * 32 + mi * 16 + (lane >> 4) * 4;
      int gn = n0 + wn * 32 + ni * 16 + (lane & 15);
      float bv = (MODE == 3 || MODE == 4) ? bias[gn] : 0.f;
      #pragma unroll
      for (int r = 0; r < 4; ++r) {
        float x = acc[mi][ni][r];
        if (MODE == 1) {
          if (gn < 512) {
            x += bias[gn];
            x = (x > 20.f) ? x : log1pf(__expf(x));
          }
        }
        if (MODE == 3 || MODE == 4) x += bv;
        float* cp = C + (size_t)(gm + r) * ldc + gn;
        if (MODE == 2 || MODE == 4) *cp += x; else *cp = x;
      }
    }
  }
}

// ---------------- depthwise causal conv (both directions) + silu ----------------
__global__ void conv_k(const float* __restrict__ XZ, const float* __restrict__ cw,
                       const float* __restrict__ cb, float* __restrict__ UC) {
  int idx = blockIdx.x * 256 + threadIdx.x;
  if (idx >= L_ * E_) return;
  int e = idx & (E_ - 1);
  int l = idx >> 9;
  float w0 = cw[0 * E_ + e], w1 = cw[1 * E_ + e];
  float w2 = cw[2 * E_ + e], w3 = cw[3 * E_ + e];
  float b = cb[e];
  float af = b, ab = b;
  #pragma unroll
  for (int k = 0; k < 4; ++k) {
    int j = l - 3 + k;
    if (j >= 0) {
      float wk = (k == 0) ? w0 : (k == 1) ? w1 : (k == 2) ? w2 : w3;
      af += wk * XZ[(size_t)j * 1024 + e];
      ab += wk * XZ[(size_t)(L_ - 1 - j) * 1024 + e];
    }
  }
  UC[idx] = siluf(af);
  UC[L_ * E_ + idx] = siluf(ab);
}

// ---------------- selective scan: thread=(dir,e), 16 states in regs ----------------
__global__ __launch_bounds__(256) void scan1_k(
    const float* __restrict__ PRDb, const float* __restrict__ UCb,
    const float* __restrict__ alog, float* __restrict__ SP, float* __restrict__ SH) {
  int b = blockIdx.x;
  int eg = b & 1, chunk = (b >> 1) & (CH - 1), dir = b >> 7;
  int e = eg * 256 + threadIdx.x;
  int l0 = chunk * CL;
  const float* prd = PRDb + (size_t)dir * L_ * 576;
  const float* ucp = UCb + (size_t)dir * L_ * E_;
  __shared__ float B_s[CL][16];
  for (int i = threadIdx.x; i < CL * 16; i += 256) {
    int l = i >> 4, n = i & 15;
    B_s[l][n] = prd[(size_t)(l0 + l) * 576 + 512 + n];
  }
  float A[16];
  #pragma unroll
  for (int n = 0; n < 16; n += 4) {
    float4 v = *(const float4*)&alog[(size_t)e * 16 + n];
    A[n] = -__expf(v.x); A[n+1] = -__expf(v.y); A[n+2] = -__expf(v.z); A[n+3] = -__expf(v.w);
  }
  float h[16];
  #pragma unroll
  for (int n = 0; n < 16; ++n) h[n] = 0.f;
  float sd = 0.f;
  __syncthreads();
  #pragma unroll
  for (int t = 0; t < CL; t += 8) {
    float d[8], u[8];
    #pragma unroll
    for (int j = 0; j < 8; ++j) {
      d[j] = prd[(size_t)(l0 + t + j) * 576 + e];
      u[j] = ucp[(size_t)(l0 + t + j) * E_ + e];
    }
    #pragma unroll
    for (int j = 0; j < 8; ++j) {
      float du = d[j] * u[j];
      sd += d[j];
      #pragma unroll
      for (int n = 0; n < 16; ++n)
        h[n] = fmaf(__expf(d[j] * A[n]), h[n], du * B_s[t + j][n]);
    }
  }
  size_t idx = ((size_t)(dir * CH + chunk) * 8192) + (size_t)e * 16;
  #pragma unroll
  for (int n = 0; n < 16; ++n) {
    SP[idx + n] = __expf(A[n] * sd);
    SH[idx + n] = h[n];
  }
}

__global__ void scan2_k(float* __restrict__ SP, const float* __restrict__ SH) {
  int idx = blockIdx.x * 256 + threadIdx.x;  // 2*8192
  if (idx >= 2 * E_ * 16) return;
  int dir = idx >> 13, en = idx & 8191;
  float c = 0.f;
  #pragma unroll
  for (int j = 0; j < CH; ++j) {
    size_t s = (size_t)(dir * CH + j) * 8192 + en;
    float p = SP[s], hh = SH[s];
    SP[s] = c;
    c = p * c + hh;
  }
}

__global__ __launch_bounds__(256) void scan3_k(
    const float* __restrict__ PRDb, const float* __restrict__ UCb,
    const float* __restrict__ alog, const float* __restrict__ dp,
    const float* __restrict__ CIN, float* __restrict__ Y2) {
  int b = blockIdx.x;
  int eg = b & 1, chunk = (b >> 1) & (CH - 1), dir = b >> 7;
  int e = eg * 256 + threadIdx.x;
  int l0 = chunk * CL;
  const float* prd = PRDb + (size_t)dir * L_ * 576;
  const float* ucp = UCb + (size_t)dir * L_ * E_;
  float* Y = Y2 + (size_t)dir * L_ * E_;
  __shared__ float B_s[CL][16], C_s[CL][16];
  for (int i = threadIdx.x; i < CL * 16; i += 256) {
    int l = i >> 4, n = i & 15;
    B_s[l][n] = prd[(size_t)(l0 + l) * 576 + 512 + n];
    C_s[l][n] = prd[(size_t)(l0 + l) * 576 + 528 + n];
  }
  float A[16];
  #pragma unroll
  for (int n = 0; n < 16; n += 4) {
    float4 v = *(const float4*)&alog[(size_t)e * 16 + n];
    A[n] = -__expf(v.x); A[n+1] = -__expf(v.y); A[n+2] = -__expf(v.z); A[n+3] = -__expf(v.w);
  }
  float D = dp[e];
  float h[16];
  {
    size_t idx = ((size_t)(dir * CH + chunk) * 8192) + (size_t)e * 16;
    #pragma unroll
    for (int n = 0; n < 16; n += 4) {
      float4 v = *(const float4*)&CIN[idx + n];
      h[n] = v.x; h[n+1] = v.y; h[n+2] = v.z; h[n+3] = v.w;
    }
  }
  __syncthreads();
  #pragma unroll
  for (int t = 0; t < CL; t += 8) {
    float d[8], u[8];
    #pragma unroll
    for (int j = 0; j < 8; ++j) {
      d[j] = prd[(size_t)(l0 + t + j) * 576 + e];
      u[j] = ucp[(size_t)(l0 + t + j) * E_ + e];
    }
    #pragma unroll
    for (int j = 0; j < 8; ++j) {
      float du = d[j] * u[j];
      float y0 = 0.f, y1 = 0.f, y2 = 0.f, y3 = 0.f;
      #pragma unroll
      for (int n = 0; n < 16; n += 4) {
        h[n]   = fmaf(__expf(d[j] * A[n]),   h[n],   du * B_s[t + j][n]);
        h[n+1] = fmaf(__expf(d[j] * A[n+1]), h[n+1], du * B_s[t + j][n+1]);
        h[n+2] = fmaf(__expf(d[j] * A[n+2]), h[n+2], du * B_s[t + j][n+2]);
        h[n+3] = fmaf(__expf(d[j] * A[n+3]), h[n+3], du * B_s[t + j][n+3]);
        y0 = fmaf(h[n],   C_s[t + j][n],   y0);
        y1 = fmaf(h[n+1], C_s[t + j][n+1], y1);
        y2 = fmaf(h[n+2], C_s[t + j][n+2], y2);
        y3 = fmaf(h[n+3], C_s[t + j][n+3], y3);
      }
      Y[(size_t)(l0 + t + j) * E_ + e] = (y0 + y1) + (y2 + y3) + u[j] * D;
    }
  }
}

// ---------------- cross-attention core ----------------
__global__ __launch_bounds__(256) void attn_k(
    const float* __restrict__ Q, const float* __restrict__ te,
    const float* __restrict__ kw, const float* __restrict__ vw, const float* __restrict__ vb,
    float* __restrict__ AO) {
  int lane = threadIdx.x & 63, h = threadIdx.x >> 6;
  int l0 = blockIdx.x * 8;
  const float* kp0 = kw + (size_t)lane * DM_ + h * 64;
  const float* vp0 = vw + h * 64 + lane;
  float vbv = vb[h * 64 + lane];
  for (int p = 0; p < 8; ++p) {
    int l = l0 + p;
    float q = Q[(size_t)l * DM_ + h * 64 + lane];
    float g = 0.f;
    #pragma unroll
    for (int d0 = 0; d0 < 64; d0 += 4) {
      float4 r = *(const float4*)(kp0 + d0);
      g = fmaf(r.x, __shfl(q, d0 + 0), g);
      g = fmaf(r.y, __shfl(q, d0 + 1), g);
      g = fmaf(r.z, __shfl(q, d0 + 2), g);
      g = fmaf(r.w, __shfl(q, d0 + 3), g);
    }
    float tfv[8], pv[8];
    #pragma unroll
    for (int t = 0; t < 8; ++t) {
      tfv[t] = te[(size_t)t * L_ * 64 + (size_t)l * 64 + lane];
      pv[t] = tfv[t] * g;
    }
    #pragma unroll
    for (int t = 0; t < 8; ++t) {
      #pragma unroll
      for (int off = 1; off < 64; off <<= 1) pv[t] += __shfl_xor(pv[t], off);
    }
    float mx = pv[0];
    #pragma unroll
    for (int t = 1; t < 8; ++t) mx = fmaxf(mx, pv[t]);
    float s = 0.f;
    #pragma unroll
    for (int t = 0; t < 8; ++t) { pv[t] = __expf((pv[t] - mx) * 0.125f); s += pv[t]; }
    float inv = 1.f / s;
    float m = 0.f;
    #pragma unroll
    for (int t = 0; t < 8; ++t) m = fmaf(pv[t] * inv, tfv[t], m);
    float o = vbv;
    #pragma unroll 8
    for (int c = 0; c < 64; ++c)
      o = fmaf(__shfl(m, c), vp0[(size_t)c * DM_], o);
    AO[(size_t)l * DM_ + h * 64 + lane] = o;
  }
}

extern "C" void kernel_launch(void* const* d_in, const int* in_sizes, int n_in,
                              void* d_out, int out_size, void* d_ws, size_t ws_size,
                              hipStream_t stream) {
  (void)in_sizes; (void)n_in; (void)out_size; (void)ws_size;
  const float* x_in = (const float*)d_in[0];
  const float* te   = (const float*)d_in[1];
  const float* mnw  = (const float*)d_in[2];
  const float* ipw  = (const float*)d_in[3];
  const float* cw   = (const float*)d_in[4];
  const float* cb   = (const float*)d_in[5];
  const float* xpw  = (const float*)d_in[6];
  const float* dpw  = (const float*)d_in[7];
  const float* dpb  = (const float*)d_in[8];
  const float* alog = (const float*)d_in[9];
  const float* dprm = (const float*)d_in[10];
  const float* opw  = (const float*)d_in[11];
  const float* cnw  = (const float*)d_in[12];
  const float* qw   = (const float*)d_in[13];
  const float* qb   = (const float*)d_in[14];
  const float* kw   = (const float*)d_in[15];
  // d_in[16] = k_b: constant over tracks -> softmax-invariant, unused
  const float* vw   = (const float*)d_in[17];
  const float* vb   = (const float*)d_in[18];
  const float* ow   = (const float*)d_in[19];
  const float* ob   = (const float*)d_in[20];

  float* ws = (float*)d_ws;
  float* X   = ws + 0;          // 524288
  float* XZ  = ws + 524288;     // 2097152
  float* UC  = ws + 2621440;    // 2097152 (dir0, dir1)
  float* PRD = ws + 4718592;    // 2359296 = 2 x 2048 x 576
  float* Y2  = ws + 7077888;    // 2097152
  float* SP  = ws + 9175040;    // 1048576
  float* SH  = ws + 10223616;   // 1048576
  unsigned short* ipwT = (unsigned short*)(ws + 11272192);  // 524288 fl
  unsigned short* WXT  = (unsigned short*)(ws + 11796480);  // 589824 fl
  unsigned short* opwT = (unsigned short*)(ws + 12386304);  // 262144 fl
  unsigned short* qwT  = (unsigned short*)(ws + 12648448);  // 65536 fl
  unsigned short* owT  = (unsigned short*)(ws + 12713984);  // 65536 fl
  float* RN = ws + 12779520;    // 2048 (16B-aligned)
  // end: 12781568 floats = 51.1 MB
  float* Qb = SP;  // alias SP (dead in CA phase)
  float* AO = SH;  // alias SH (dead in CA phase)

  tcast_k<<<dim3(32, 8, 4), 256, 0, stream>>>(ipw, ipwT, 256, 1024);
  tcast_k<<<dim3(8, 16, 4), 256, 0, stream>>>(opw, opwT, 512, 256);
  tcast_k<<<dim3(8, 8, 2), 256, 0, stream>>>(qw, qwT, 256, 256);
  tcast_k<<<dim3(8, 8, 2), 256, 0, stream>>>(ow, owT, 256, 256);
  wdt_k<<<dim3(1152, 4), 256, 0, stream>>>(xpw, dpw, WXT);

  hipMemcpyAsync(X, x_in, (size_t)L_ * DM_ * sizeof(float),
                 hipMemcpyDeviceToDevice, stream);

  for (int i = 0; i < 4; ++i) {
    rnorm_k<<<512, 256, 0, stream>>>(X, RN);
    mgemm_k<1,0><<<dim3(16, 32, 1), 256, 0, stream>>>(
        X, 256, 0, RN, mnw + i * 256, ipwT + (size_t)i * 1024 * 256, nullptr,
        XZ, 1024, 0, 256);
    conv_k<<<4096, 256, 0, stream>>>(XZ, cw + i * 4 * 512, cb + i * 512, UC);
    mgemm_k<0,1><<<dim3(9, 32, 2), 256, 0, stream>>>(
        UC, 512, 1048576, nullptr, nullptr, WXT + (size_t)i * 576 * 512, dpb + i * 512,
        PRD, 576, 1179648, 512);
    scan1_k<<<2 * CH * 2, 256, 0, stream>>>(PRD, UC, alog + (size_t)i * 512 * 16, SP, SH);
    scan2_k<<<64, 256, 0, stream>>>(SP, SH);
    scan3_k<<<2 * CH * 2, 256, 0, stream>>>(PRD, UC, alog + (size_t)i * 512 * 16,
                                            dprm + i * 512, SP, Y2);
    mgemm_k<2,2><<<dim3(4, 32, 1), 256, 0, stream>>>(
        Y2, 512, 0, XZ + 512, nullptr, opwT + (size_t)i * 256 * 512, nullptr,
        X, 256, 0, 512);

    if (i == 1 || i == 3) {
      int j = (i == 1) ? 0 : 1;
      rnorm_k<<<512, 256, 0, stream>>>(X, RN);
      mgemm_k<1,3><<<dim3(4, 32, 1), 256, 0, stream>>>(
          X, 256, 0, RN, cnw + j * 256, qwT + (size_t)j * 256 * 256, qb + j * 256,
          Qb, 256, 0, 256);
      attn_k<<<256, 256, 0, stream>>>(Qb, te, kw + (size_t)j * 64 * 256,
                                      vw + (size_t)j * 64 * 256, vb + j * 256, AO);
      mgemm_k<0,4><<<dim3(4, 32, 1), 256, 0, stream>>>(
          AO, 256, 0, nullptr, nullptr, owT + (size_t)j * 256 * 256, ob + j * 256,
          X, 256, 0, 256);
    }
  }

  hipMemcpyAsync(d_out, X, (size_t)L_ * DM_ * sizeof(float),
                 hipMemcpyDeviceToDevice, stream);
}

// Round 8
// 527.149 us; speedup vs baseline: 1.0876x; 1.0097x over previous
//
#include <hip/hip_runtime.h>
#include <hip/hip_bf16.h>

// MambaTower: B=1, L=2048, DM=256, E=512, N=16, R=16, K=4, NL=4, CA at layers 1,3
// fp32 tensors; GEMMs via bf16 MFMA (BK=64 — BK=128 measured -68us regression R6);
// dt_proj folded into x_proj; rmsnorm computed IN-GEMM; combine folded into A-staging.
// Scan: thread=(dir,e), 16 states in registers. 36 dispatches total.

constexpr int L_ = 2048, DM_ = 256, E_ = 512;
constexpr int CH = 64, CL = 32;  // scan chunks x chunk length (CH*CL == L_)

typedef __attribute__((ext_vector_type(8))) short bf16x8;
typedef __attribute__((ext_vector_type(4))) float f32x4;

__device__ __forceinline__ float siluf(float x) { return x / (1.f + __expf(-x)); }
__device__ __forceinline__ unsigned short f2b(float f) {
  union { float f; unsigned u; } x; x.f = f;
  unsigned r = x.u + 0x7fff + ((x.u >> 16) & 1);
  return (unsigned short)(r >> 16);
}

// ---------------- merged weight prep: all transposes + wdt in ONE kernel ----------------
// blocks: [0,1024) ipw | [1024,1536) opw | [1536,1664) qw | [1664,1792) ow | [1792,6400) wdt
__global__ __launch_bounds__(256) void wprep_k(
    const float* __restrict__ ipw, const float* __restrict__ opw,
    const float* __restrict__ qw,  const float* __restrict__ ow,
    const float* __restrict__ xpw, const float* __restrict__ dpw,
    unsigned short* __restrict__ ipwT, unsigned short* __restrict__ opwT,
    unsigned short* __restrict__ qwT,  unsigned short* __restrict__ owT,
    unsigned short* __restrict__ WXT) {
  __shared__ float t[32][33];
  int b = blockIdx.x;
  const float* in = nullptr; unsigned short* out = nullptr;
  int K = 0, N = 0, bx = 0, by = 0;
  if (b < 1024) {        // ipw: K=256 N=1024, 4 layers, 32x8 tiles
    int z = b >> 8, tt = b & 255;
    in = ipw + (size_t)z * 256 * 1024; out = ipwT + (size_t)z * 256 * 1024;
    K = 256; N = 1024; bx = tt & 31; by = tt >> 5;
  } else if (b < 1536) { // opw: K=512 N=256, 4 layers, 8x16 tiles
    int z = (b - 1024) >> 7, tt = (b - 1024) & 127;
    in = opw + (size_t)z * 512 * 256; out = opwT + (size_t)z * 512 * 256;
    K = 512; N = 256; bx = tt & 7; by = tt >> 3;
  } else if (b < 1664) { // qw: K=256 N=256, 2 layers, 8x8 tiles
    int z = (b - 1536) >> 6, tt = (b - 1536) & 63;
    in = qw + (size_t)z * 256 * 256; out = qwT + (size_t)z * 256 * 256;
    K = 256; N = 256; bx = tt & 7; by = tt >> 3;
  } else if (b < 1792) { // ow
    int z = (b - 1664) >> 6, tt = (b - 1664) & 63;
    in = ow + (size_t)z * 256 * 256; out = owT + (size_t)z * 256 * 256;
    K = 256; N = 256; bx = tt & 7; by = tt >> 3;
  } else {               // wdt: [Wdt^T | xwBC^T | 0pad] bf16 [576][512], 4 layers x 1152
    int bp = b - 1792;
    int l = bp / 1152, bb = bp % 1152;
    const float* xw = xpw + (size_t)l * 512 * 48;
    const float* dw = dpw + (size_t)l * 16 * 512;
    unsigned short* o = WXT + (size_t)l * 576 * 512;
    int tI = threadIdx.x;
    if (bb < 1024) {
      int idx = bb * 256 + tI;
      int k = idx & 511, n = idx >> 9;
      float s = 0.f;
      #pragma unroll
      for (int r = 0; r < 16; ++r) s = fmaf(xw[k * 48 + r], dw[r * 512 + n], s);
      o[(size_t)n * 512 + k] = f2b(s);
    } else if (bb < 1088) {
      int idx = (bb - 1024) * 256 + tI;
      int k = idx & 511, j = idx >> 9;
      o[(size_t)(512 + j) * 512 + k] = f2b(xw[k * 48 + 16 + j]);
    } else {
      int idx = (bb - 1088) * 256 + tI;
      int k = idx & 511, j = idx >> 9;
      o[(size_t)(544 + j) * 512 + k] = 0;
    }
    return;
  }
  // 32x32 tiled transpose+cast: out[n][k] = bf16(in[k][n])
  int n0 = bx * 32, k0 = by * 32;
  int tx = threadIdx.x & 31, ty = threadIdx.x >> 5;
  #pragma unroll
  for (int i = 0; i < 32; i += 8)
    t[ty + i][tx] = in[(size_t)(k0 + ty + i) * N + n0 + tx];
  __syncthreads();
  #pragma unroll
  for (int i = 0; i < 32; i += 8)
    out[(size_t)(n0 + ty + i) * K + k0 + tx] = f2b(t[tx][ty + i]);
}

// ---------------- MFMA GEMM: C[2048 x N] = op(srcA * BT^T), BK=64 ----------------
// AMODE: 0 plain A[row*lda+k]
//        1 fused rmsnorm: in-kernel rn over full row (requires lda==Kd), Aux2=norm w
//        2 combine: (Y2f[row*512+k]+Y2b[(2047-row)*512+k])*silu(Z[row*1024+k]), Aux1=XZ+512
// MODE:  0 store | 1 softplus(v+bias) gn<512 else store | 2 C+=v | 3 store v+bias
//        4 C+=v+bias | 5 C = Aux1[idx] + v + bias  (residual redirect, Aux1=X, C=d_out)
template<int AMODE, int MODE>
__global__ __launch_bounds__(256) void mgemm_k(
    const float* __restrict__ A, int lda, size_t saz,
    const float* __restrict__ Aux1, const float* __restrict__ Aux2,
    const unsigned short* __restrict__ BT,
    const float* __restrict__ bias,
    float* __restrict__ C, int ldc, size_t scz,
    int Kd) {
  A += (size_t)blockIdx.z * saz;
  C += (size_t)blockIdx.z * scz;
  __shared__ unsigned short Als[64 * 64];
  __shared__ unsigned short Bls[64 * 64];
  const int tid = threadIdx.x;
  const int lane = tid & 63, wave = tid >> 6;
  const int wm = wave >> 1, wn = wave & 1;
  const int m0 = blockIdx.y * 64, n0 = blockIdx.x * 64;
  const int srow = tid >> 2, sc = tid & 3;
  const unsigned swz = (unsigned)((srow & 7) << 4);
  const int arow = m0 + srow;
  float rnv = 0.f;
  if (AMODE == 1) {  // in-kernel rms: each row's 4 sc-threads scan the full row
    const float* xp = A + (size_t)arow * lda;
    float ssq = 0.f;
    for (int k0 = 0; k0 < Kd; k0 += 64) {
      #pragma unroll
      for (int i = 0; i < 4; ++i) {
        float4 v = *(const float4*)(xp + k0 + sc * 16 + i * 4);
        ssq += v.x * v.x + v.y * v.y + v.z * v.z + v.w * v.w;
      }
    }
    ssq += __shfl_xor(ssq, 1);
    ssq += __shfl_xor(ssq, 2);
    rnv = rsqrtf(ssq * (1.f / (float)Kd) + 1e-6f);
  }
  f32x4 acc[2][2] = {};
  for (int k0 = 0; k0 < Kd; k0 += 64) {
    __syncthreads();
    // stage A: 16 fp32 -> bf16 per thread
    #pragma unroll
    for (int i = 0; i < 4; ++i) {
      int k = sc * 16 + i * 4;
      float4 v;
      if (AMODE == 2) {
        float4 yf = *(const float4*)(A + (size_t)arow * 512 + k0 + k);
        float4 yb = *(const float4*)(A + (size_t)L_ * E_ + (size_t)(2047 - arow) * 512 + k0 + k);
        float4 z  = *(const float4*)(Aux1 + (size_t)arow * 1024 + k0 + k);
        v.x = (yf.x + yb.x) * siluf(z.x);
        v.y = (yf.y + yb.y) * siluf(z.y);
        v.z = (yf.z + yb.z) * siluf(z.z);
        v.w = (yf.w + yb.w) * siluf(z.w);
      } else {
        v = *(const float4*)(A + (size_t)arow * lda + k0 + k);
        if (AMODE == 1) {
          float4 w4 = *(const float4*)(Aux2 + k0 + k);
          v.x *= rnv * w4.x; v.y *= rnv * w4.y; v.z *= rnv * w4.z; v.w *= rnv * w4.w;
        }
      }
      uint2 p;
      p.x = (unsigned)f2b(v.x) | ((unsigned)f2b(v.y) << 16);
      p.y = (unsigned)f2b(v.z) | ((unsigned)f2b(v.w) << 16);
      unsigned off = (unsigned)(srow * 128 + k * 2) ^ swz;
      *(uint2*)((char*)Als + off) = p;
    }
    // stage B: 16 bf16 per thread (2 x 16B)
    {
      const unsigned short* bp = BT + (size_t)(n0 + srow) * Kd + k0 + sc * 8;
      #pragma unroll
      for (int i = 0; i < 2; ++i) {
        uint4 v = *(const uint4*)(bp + i * 32);
        unsigned off = (unsigned)(srow * 128 + (sc * 8 + i * 32) * 2) ^ swz;
        *(uint4*)((char*)Bls + off) = v;
      }
    }
    __syncthreads();
    #pragma unroll
    for (int ks = 0; ks < 64; ks += 32) {
      bf16x8 af[2], bfr[2];
      #pragma unroll
      for (int mi = 0; mi < 2; ++mi) {
        int row = wm * 32 + mi * 16 + (lane & 15);
        unsigned off = (unsigned)(row * 128 + (ks + (lane >> 4) * 8) * 2) ^ ((unsigned)((row & 7) << 4));
        af[mi] = *(const bf16x8*)((const char*)Als + off);
      }
      #pragma unroll
      for (int ni = 0; ni < 2; ++ni) {
        int row = wn * 32 + ni * 16 + (lane & 15);
        unsigned off = (unsigned)(row * 128 + (ks + (lane >> 4) * 8) * 2) ^ ((unsigned)((row & 7) << 4));
        bfr[ni] = *(const bf16x8*)((const char*)Bls + off);
      }
      #pragma unroll
      for (int mi = 0; mi < 2; ++mi)
        #pragma unroll
        for (int ni = 0; ni < 2; ++ni)
          acc[mi][ni] = __builtin_amdgcn_mfma_f32_16x16x32_bf16(af[mi], bfr[ni], acc[mi][ni], 0, 0, 0);
    }
  }
  #pragma unroll
  for (int mi = 0; mi < 2; ++mi) {
    #pragma unroll
    for (int ni = 0; ni < 2; ++ni) {
      int gm = m0 + wm * 32 + mi * 16 + (lane >> 4) * 4;
      int gn = n0 + wn * 32 + ni * 16 + (lane & 15);
      float bv = (MODE == 3 || MODE == 4 || MODE == 5) ? bias[gn] : 0.f;
      #pragma unroll
      for (int r = 0; r < 4; ++r) {
        float x = acc[mi][ni][r];
        if (MODE == 1) {
          if (gn < 512) {
            x += bias[gn];
            x = (x > 20.f) ? x : log1pf(__expf(x));
          }
        }
        if (MODE == 3 || MODE == 4 || MODE == 5) x += bv;
        size_t ci = (size_t)(gm + r) * ldc + gn;
        if (MODE == 5)      C[ci] = Aux1[ci] + x;
        else if (MODE == 2 || MODE == 4) C[ci] += x;
        else                C[ci] = x;
      }
    }
  }
}

// ---------------- depthwise causal conv (both directions) + silu, float4 ----------------
__global__ void conv_k(const float* __restrict__ XZ, const float* __restrict__ cw,
                       const float* __restrict__ cb, float* __restrict__ UC) {
  int idx = blockIdx.x * 256 + threadIdx.x;  // over L*E/4
  int e = (idx & 127) * 4;
  int l = idx >> 7;
  float4 w[4];
  #pragma unroll
  for (int k = 0; k < 4; ++k) w[k] = *(const float4*)(cw + k * 512 + e);
  float4 bb = *(const float4*)(cb + e);
  float4 af = bb, ab = bb;
  #pragma unroll
  for (int k = 0; k < 4; ++k) {
    int j = l - 3 + k;
    if (j >= 0) {
      float4 xf = *(const float4*)(XZ + (size_t)j * 1024 + e);
      float4 xb = *(const float4*)(XZ + (size_t)(2047 - j) * 1024 + e);
      af.x = fmaf(w[k].x, xf.x, af.x); af.y = fmaf(w[k].y, xf.y, af.y);
      af.z = fmaf(w[k].z, xf.z, af.z); af.w = fmaf(w[k].w, xf.w, af.w);
      ab.x = fmaf(w[k].x, xb.x, ab.x); ab.y = fmaf(w[k].y, xb.y, ab.y);
      ab.z = fmaf(w[k].z, xb.z, ab.z); ab.w = fmaf(w[k].w, xb.w, ab.w);
    }
  }
  float4 of, ob;
  of.x = siluf(af.x); of.y = siluf(af.y); of.z = siluf(af.z); of.w = siluf(af.w);
  ob.x = siluf(ab.x); ob.y = siluf(ab.y); ob.z = siluf(ab.z); ob.w = siluf(ab.w);
  *(float4*)(UC + (size_t)l * 512 + e) = of;
  *(float4*)(UC + (size_t)L_ * E_ + (size_t)l * 512 + e) = ob;
}

// ---------------- selective scan: thread=(dir,e), 16 states in regs ----------------
__global__ __launch_bounds__(256) void scan1_k(
    const float* __restrict__ PRDb, const float* __restrict__ UCb,
    const float* __restrict__ alog, float* __restrict__ SP, float* __restrict__ SH) {
  int b = blockIdx.x;
  int eg = b & 1, chunk = (b >> 1) & (CH - 1), dir = b >> 7;
  int e = eg * 256 + threadIdx.x;
  int l0 = chunk * CL;
  const float* prd = PRDb + (size_t)dir * L_ * 576;
  const float* ucp = UCb + (size_t)dir * L_ * E_;
  __shared__ float B_s[CL][16];
  for (int i = threadIdx.x; i < CL * 16; i += 256) {
    int l = i >> 4, n = i & 15;
    B_s[l][n] = prd[(size_t)(l0 + l) * 576 + 512 + n];
  }
  float A[16];
  #pragma unroll
  for (int n = 0; n < 16; n += 4) {
    float4 v = *(const float4*)&alog[(size_t)e * 16 + n];
    A[n] = -__expf(v.x); A[n+1] = -__expf(v.y); A[n+2] = -__expf(v.z); A[n+3] = -__expf(v.w);
  }
  float h[16];
  #pragma unroll
  for (int n = 0; n < 16; ++n) h[n] = 0.f;
  float sd = 0.f;
  __syncthreads();
  #pragma unroll
  for (int t = 0; t < CL; t += 8) {
    float d[8], u[8];
    #pragma unroll
    for (int j = 0; j < 8; ++j) {
      d[j] = prd[(size_t)(l0 + t + j) * 576 + e];
      u[j] = ucp[(size_t)(l0 + t + j) * E_ + e];
    }
    #pragma unroll
    for (int j = 0; j < 8; ++j) {
      float du = d[j] * u[j];
      sd += d[j];
      #pragma unroll
      for (int n = 0; n < 16; ++n)
        h[n] = fmaf(__expf(d[j] * A[n]), h[n], du * B_s[t + j][n]);
    }
  }
  size_t idx = ((size_t)(dir * CH + chunk) * 8192) + (size_t)e * 16;
  #pragma unroll
  for (int n = 0; n < 16; ++n) {
    SP[idx + n] = __expf(A[n] * sd);
    SH[idx + n] = h[n];
  }
}

__global__ void scan2_k(float* __restrict__ SP, const float* __restrict__ SH) {
  int idx = blockIdx.x * 256 + threadIdx.x;  // 2*8192
  if (idx >= 2 * E_ * 16) return;
  int dir = idx >> 13, en = idx & 8191;
  float c = 0.f;
  #pragma unroll
  for (int j = 0; j < CH; ++j) {
    size_t s = (size_t)(dir * CH + j) * 8192 + en;
    float p = SP[s], hh = SH[s];
    SP[s] = c;
    c = p * c + hh;
  }
}

__global__ __launch_bounds__(256) void scan3_k(
    const float* __restrict__ PRDb, const float* __restrict__ UCb,
    const float* __restrict__ alog, const float* __restrict__ dp,
    const float* __restrict__ CIN, float* __restrict__ Y2) {
  int b = blockIdx.x;
  int eg = b & 1, chunk = (b >> 1) & (CH - 1), dir = b >> 7;
  int e = eg * 256 + threadIdx.x;
  int l0 = chunk * CL;
  const float* prd = PRDb + (size_t)dir * L_ * 576;
  const float* ucp = UCb + (size_t)dir * L_ * E_;
  float* Y = Y2 + (size_t)dir * L_ * E_;
  __shared__ float B_s[CL][16], C_s[CL][16];
  for (int i = threadIdx.x; i < CL * 16; i += 256) {
    int l = i >> 4, n = i & 15;
    B_s[l][n] = prd[(size_t)(l0 + l) * 576 + 512 + n];
    C_s[l][n] = prd[(size_t)(l0 + l) * 576 + 528 + n];
  }
  float A[16];
  #pragma unroll
  for (int n = 0; n < 16; n += 4) {
    float4 v = *(const float4*)&alog[(size_t)e * 16 + n];
    A[n] = -__expf(v.x); A[n+1] = -__expf(v.y); A[n+2] = -__expf(v.z); A[n+3] = -__expf(v.w);
  }
  float D = dp[e];
  float h[16];
  {
    size_t idx = ((size_t)(dir * CH + chunk) * 8192) + (size_t)e * 16;
    #pragma unroll
    for (int n = 0; n < 16; n += 4) {
      float4 v = *(const float4*)&CIN[idx + n];
      h[n] = v.x; h[n+1] = v.y; h[n+2] = v.z; h[n+3] = v.w;
    }
  }
  __syncthreads();
  #pragma unroll
  for (int t = 0; t < CL; t += 8) {
    float d[8], u[8];
    #pragma unroll
    for (int j = 0; j < 8; ++j) {
      d[j] = prd[(size_t)(l0 + t + j) * 576 + e];
      u[j] = ucp[(size_t)(l0 + t + j) * E_ + e];
    }
    #pragma unroll
    for (int j = 0; j < 8; ++j) {
      float du = d[j] * u[j];
      float y0 = 0.f, y1 = 0.f, y2 = 0.f, y3 = 0.f;
      #pragma unroll
      for (int n = 0; n < 16; n += 4) {
        h[n]   = fmaf(__expf(d[j] * A[n]),   h[n],   du * B_s[t + j][n]);
        h[n+1] = fmaf(__expf(d[j] * A[n+1]), h[n+1], du * B_s[t + j][n+1]);
        h[n+2] = fmaf(__expf(d[j] * A[n+2]), h[n+2], du * B_s[t + j][n+2]);
        h[n+3] = fmaf(__expf(d[j] * A[n+3]), h[n+3], du * B_s[t + j][n+3]);
        y0 = fmaf(h[n],   C_s[t + j][n],   y0);
        y1 = fmaf(h[n+1], C_s[t + j][n+1], y1);
        y2 = fmaf(h[n+2], C_s[t + j][n+2], y2);
        y3 = fmaf(h[n+3], C_s[t + j][n+3], y3);
      }
      Y[(size_t)(l0 + t + j) * E_ + e] = (y0 + y1) + (y2 + y3) + u[j] * D;
    }
  }
}

// ---------------- cross-attention core (kw/vw hoisted to registers) ----------------
__global__ __launch_bounds__(256) void attn_k(
    const float* __restrict__ Q, const float* __restrict__ te,
    const float* __restrict__ kw, const float* __restrict__ vw, const float* __restrict__ vb,
    float* __restrict__ AO) {
  int lane = threadIdx.x & 63, h = threadIdx.x >> 6;
  int l0 = blockIdx.x * 4;  // grid 512
  const float* kp0 = kw + (size_t)lane * DM_ + h * 64;
  const float* vp0 = vw + h * 64 + lane;
  float vbv = vb[h * 64 + lane];
  float4 kf[16];
  #pragma unroll
  for (int i = 0; i < 16; ++i) kf[i] = *(const float4*)(kp0 + i * 4);
  float vv[64];
  #pragma unroll
  for (int c = 0; c < 64; ++c) vv[c] = vp0[(size_t)c * DM_];
  for (int p = 0; p < 4; ++p) {
    int l = l0 + p;
    float q = Q[(size_t)l * DM_ + h * 64 + lane];
    float g = 0.f;
    #pragma unroll
    for (int d0 = 0; d0 < 64; d0 += 4) {
      float4 r = kf[d0 >> 2];
      g = fmaf(r.x, __shfl(q, d0 + 0), g);
      g = fmaf(r.y, __shfl(q, d0 + 1), g);
      g = fmaf(r.z, __shfl(q, d0 + 2), g);
      g = fmaf(r.w, __shfl(q, d0 + 3), g);
    }
    float tfv[8], pv[8];
    #pragma unroll
    for (int t = 0; t < 8; ++t) {
      tfv[t] = te[(size_t)t * L_ * 64 + (size_t)l * 64 + lane];
      pv[t] = tfv[t] * g;
    }
    #pragma unroll
    for (int t = 0; t < 8; ++t) {
      #pragma unroll
      for (int off = 1; off < 64; off <<= 1) pv[t] += __shfl_xor(pv[t], off);
    }
    float mx = pv[0];
    #pragma unroll
    for (int t = 1; t < 8; ++t) mx = fmaxf(mx, pv[t]);
    float s = 0.f;
    #pragma unroll
    for (int t = 0; t < 8; ++t) { pv[t] = __expf((pv[t] - mx) * 0.125f); s += pv[t]; }
    float inv = 1.f / s;
    float m = 0.f;
    #pragma unroll
    for (int t = 0; t < 8; ++t) m = fmaf(pv[t] * inv, tfv[t], m);
    float o = vbv;
    #pragma unroll 8
    for (int c = 0; c < 64; ++c)
      o = fmaf(__shfl(m, c), vv[c], o);
    AO[(size_t)l * DM_ + h * 64 + lane] = o;
  }
}

extern "C" void kernel_launch(void* const* d_in, const int* in_sizes, int n_in,
                              void* d_out, int out_size, void* d_ws, size_t ws_size,
                              hipStream_t stream) {
  (void)in_sizes; (void)n_in; (void)out_size; (void)ws_size;
  const float* x_in = (const float*)d_in[0];
  const float* te   = (const float*)d_in[1];
  const float* mnw  = (const float*)d_in[2];
  const float* ipw  = (const float*)d_in[3];
  const float* cw   = (const float*)d_in[4];
  const float* cb   = (const float*)d_in[5];
  const float* xpw  = (const float*)d_in[6];
  const float* dpw  = (const float*)d_in[7];
  const float* dpb  = (const float*)d_in[8];
  const float* alog = (const float*)d_in[9];
  const float* dprm = (const float*)d_in[10];
  const float* opw  = (const float*)d_in[11];
  const float* cnw  = (const float*)d_in[12];
  const float* qw   = (const float*)d_in[13];
  const float* qb   = (const float*)d_in[14];
  const float* kw   = (const float*)d_in[15];
  // d_in[16] = k_b: constant over tracks -> softmax-invariant, unused
  const float* vw   = (const float*)d_in[17];
  const float* vb   = (const float*)d_in[18];
  const float* ow   = (const float*)d_in[19];
  const float* ob   = (const float*)d_in[20];

  float* ws = (float*)d_ws;
  float* X   = ws + 0;          // 524288
  float* XZ  = ws + 524288;     // 2097152
  float* UC  = ws + 2621440;    // 2097152 (dir0, dir1)
  float* PRD = ws + 4718592;    // 2359296 = 2 x 2048 x 576
  float* Y2  = ws + 7077888;    // 2097152
  float* SP  = ws + 9175040;    // 1048576
  float* SH  = ws + 10223616;   // 1048576
  unsigned short* ipwT = (unsigned short*)(ws + 11272192);  // 524288 fl
  unsigned short* WXT  = (unsigned short*)(ws + 11796480);  // 589824 fl
  unsigned short* opwT = (unsigned short*)(ws + 12386304);  // 262144 fl
  unsigned short* qwT  = (unsigned short*)(ws + 12648448);  // 65536 fl
  unsigned short* owT  = (unsigned short*)(ws + 12713984);  // 65536 fl
  // end: 12779520 floats = 51.1 MB
  float* Qb = SP;  // alias SP (dead in CA phase)
  float* AO = SH;  // alias SH (dead in CA phase)

  wprep_k<<<6400, 256, 0, stream>>>(ipw, opw, qw, ow, xpw, dpw,
                                    ipwT, opwT, qwT, owT, WXT);

  hipMemcpyAsync(X, x_in, (size_t)L_ * DM_ * sizeof(float),
                 hipMemcpyDeviceToDevice, stream);

  for (int i = 0; i < 4; ++i) {
    mgemm_k<1,0><<<dim3(16, 32, 1), 256, 0, stream>>>(
        X, 256, 0, nullptr, mnw + i * 256, ipwT + (size_t)i * 1024 * 256, nullptr,
        XZ, 1024, 0, 256);
    conv_k<<<1024, 256, 0, stream>>>(XZ, cw + i * 4 * 512, cb + i * 512, UC);
    mgemm_k<0,1><<<dim3(9, 32, 2), 256, 0, stream>>>(
        UC, 512, 1048576, nullptr, nullptr, WXT + (size_t)i * 576 * 512, dpb + i * 512,
        PRD, 576, 1179648, 512);
    scan1_k<<<2 * CH * 2, 256, 0, stream>>>(PRD, UC, alog + (size_t)i * 512 * 16, SP, SH);
    scan2_k<<<64, 256, 0, stream>>>(SP, SH);
    scan3_k<<<2 * CH * 2, 256, 0, stream>>>(PRD, UC, alog + (size_t)i * 512 * 16,
                                            dprm + i * 512, SP, Y2);
    mgemm_k<2,2><<<dim3(4, 32, 1), 256, 0, stream>>>(
        Y2, 512, 0, XZ + 512, nullptr, opwT + (size_t)i * 256 * 512, nullptr,
        X, 256, 0, 512);

    if (i == 1 || i == 3) {
      int j = (i == 1) ? 0 : 1;
      mgemm_k<1,3><<<dim3(4, 32, 1), 256, 0, stream>>>(
          X, 256, 0, nullptr, cnw + j * 256, qwT + (size_t)j * 256 * 256, qb + j * 256,
          Qb, 256, 0, 256);
      attn_k<<<512, 256, 0, stream>>>(Qb, te, kw + (size_t)j * 64 * 256,
                                      vw + (size_t)j * 64 * 256, vb + j * 256, AO);
      if (i == 3) {
        // final op: residual + o-proj straight into d_out (saves the copy-out)
        mgemm_k<0,5><<<dim3(4, 32, 1), 256, 0, stream>>>(
            AO, 256, 0, X, nullptr, owT + (size_t)j * 256 * 256, ob + j * 256,
            (float*)d_out, 256, 0, 256);
      } else {
        mgemm_k<0,4><<<dim3(4, 32, 1), 256, 0, stream>>>(
            AO, 256, 0, nullptr, nullptr, owT + (size_t)j * 256 * 256, ob + j * 256,
            X, 256, 0, 256);
      }
    }
  }
}

// Round 9
// 500.903 us; speedup vs baseline: 1.1446x; 1.0524x over previous
//
#include <hip/hip_runtime.h>
#include <hip/hip_bf16.h>

// MambaTower: B=1, L=2048, DM=256, E=512, N=16, R=16, K=4, NL=4, CA at layers 1,3
// fp32 tensors; GEMMs via bf16 MFMA (BK=64 — BK=128 measured -68us regression R6);
// dt_proj folded into x_proj; rmsnorm computed IN-GEMM; combine folded into A-staging.
// Scan: thread=(dir,e), 16 states in registers. attn: NO vv[] hoist (R8: scratch, 44MB fetch).

constexpr int L_ = 2048, DM_ = 256, E_ = 512;
constexpr int CH = 64, CL = 32;  // scan chunks x chunk length (CH*CL == L_)

typedef __attribute__((ext_vector_type(8))) short bf16x8;
typedef __attribute__((ext_vector_type(4))) float f32x4;

__device__ __forceinline__ float siluf(float x) { return x / (1.f + __expf(-x)); }
__device__ __forceinline__ unsigned short f2b(float f) {
  union { float f; unsigned u; } x; x.f = f;
  unsigned r = x.u + 0x7fff + ((x.u >> 16) & 1);
  return (unsigned short)(r >> 16);
}

// ---------------- merged weight prep: all transposes + wdt in ONE kernel ----------------
// blocks: [0,1024) ipw | [1024,1536) opw | [1536,1664) qw | [1664,1792) ow | [1792,6400) wdt
__global__ __launch_bounds__(256) void wprep_k(
    const float* __restrict__ ipw, const float* __restrict__ opw,
    const float* __restrict__ qw,  const float* __restrict__ ow,
    const float* __restrict__ xpw, const float* __restrict__ dpw,
    unsigned short* __restrict__ ipwT, unsigned short* __restrict__ opwT,
    unsigned short* __restrict__ qwT,  unsigned short* __restrict__ owT,
    unsigned short* __restrict__ WXT) {
  __shared__ float t[32][33];
  int b = blockIdx.x;
  const float* in = nullptr; unsigned short* out = nullptr;
  int K = 0, N = 0, bx = 0, by = 0;
  if (b < 1024) {        // ipw: K=256 N=1024, 4 layers, 32x8 tiles
    int z = b >> 8, tt = b & 255;
    in = ipw + (size_t)z * 256 * 1024; out = ipwT + (size_t)z * 256 * 1024;
    K = 256; N = 1024; bx = tt & 31; by = tt >> 5;
  } else if (b < 1536) { // opw: K=512 N=256, 4 layers, 8x16 tiles
    int z = (b - 1024) >> 7, tt = (b - 1024) & 127;
    in = opw + (size_t)z * 512 * 256; out = opwT + (size_t)z * 512 * 256;
    K = 512; N = 256; bx = tt & 7; by = tt >> 3;
  } else if (b < 1664) { // qw: K=256 N=256, 2 layers, 8x8 tiles
    int z = (b - 1536) >> 6, tt = (b - 1536) & 63;
    in = qw + (size_t)z * 256 * 256; out = qwT + (size_t)z * 256 * 256;
    K = 256; N = 256; bx = tt & 7; by = tt >> 3;
  } else if (b < 1792) { // ow
    int z = (b - 1664) >> 6, tt = (b - 1664) & 63;
    in = ow + (size_t)z * 256 * 256; out = owT + (size_t)z * 256 * 256;
    K = 256; N = 256; bx = tt & 7; by = tt >> 3;
  } else {               // wdt: [Wdt^T | xwBC^T | 0pad] bf16 [576][512], 4 layers x 1152
    int bp = b - 1792;
    int l = bp / 1152, bb = bp % 1152;
    const float* xw = xpw + (size_t)l * 512 * 48;
    const float* dw = dpw + (size_t)l * 16 * 512;
    unsigned short* o = WXT + (size_t)l * 576 * 512;
    int tI = threadIdx.x;
    if (bb < 1024) {
      int idx = bb * 256 + tI;
      int k = idx & 511, n = idx >> 9;
      float s = 0.f;
      #pragma unroll
      for (int r = 0; r < 16; ++r) s = fmaf(xw[k * 48 + r], dw[r * 512 + n], s);
      o[(size_t)n * 512 + k] = f2b(s);
    } else if (bb < 1088) {
      int idx = (bb - 1024) * 256 + tI;
      int k = idx & 511, j = idx >> 9;
      o[(size_t)(512 + j) * 512 + k] = f2b(xw[k * 48 + 16 + j]);
    } else {
      int idx = (bb - 1088) * 256 + tI;
      int k = idx & 511, j = idx >> 9;
      o[(size_t)(544 + j) * 512 + k] = 0;
    }
    return;
  }
  // 32x32 tiled transpose+cast: out[n][k] = bf16(in[k][n])
  int n0 = bx * 32, k0 = by * 32;
  int tx = threadIdx.x & 31, ty = threadIdx.x >> 5;
  #pragma unroll
  for (int i = 0; i < 32; i += 8)
    t[ty + i][tx] = in[(size_t)(k0 + ty + i) * N + n0 + tx];
  __syncthreads();
  #pragma unroll
  for (int i = 0; i < 32; i += 8)
    out[(size_t)(n0 + ty + i) * K + k0 + tx] = f2b(t[tx][ty + i]);
}

// ---------------- MFMA GEMM: C[2048 x N] = op(srcA * BT^T), BK=64 ----------------
// AMODE: 0 plain A[row*lda+k]
//        1 fused rmsnorm: in-kernel rn over full row (requires lda==Kd), Aux2=norm w
//        2 combine: (Y2f[row*512+k]+Y2b[(2047-row)*512+k])*silu(Z[row*1024+k]), Aux1=XZ+512
// MODE:  0 store | 1 softplus(v+bias) gn<512 else store | 2 C+=v | 3 store v+bias
//        4 C+=v+bias | 5 C = Aux1[idx] + v + bias  (residual redirect, Aux1=X, C=d_out)
template<int AMODE, int MODE>
__global__ __launch_bounds__(256) void mgemm_k(
    const float* __restrict__ A, int lda, size_t saz,
    const float* __restrict__ Aux1, const float* __restrict__ Aux2,
    const unsigned short* __restrict__ BT,
    const float* __restrict__ bias,
    float* __restrict__ C, int ldc, size_t scz,
    int Kd) {
  A += (size_t)blockIdx.z * saz;
  C += (size_t)blockIdx.z * scz;
  __shared__ unsigned short Als[64 * 64];
  __shared__ unsigned short Bls[64 * 64];
  const int tid = threadIdx.x;
  const int lane = tid & 63, wave = tid >> 6;
  const int wm = wave >> 1, wn = wave & 1;
  const int m0 = blockIdx.y * 64, n0 = blockIdx.x * 64;
  const int srow = tid >> 2, sc = tid & 3;
  const unsigned swz = (unsigned)((srow & 7) << 4);
  const int arow = m0 + srow;
  float rnv = 0.f;
  if (AMODE == 1) {  // in-kernel rms: each row's 4 sc-threads scan the full row
    const float* xp = A + (size_t)arow * lda;
    float ssq = 0.f;
    for (int k0 = 0; k0 < Kd; k0 += 64) {
      #pragma unroll
      for (int i = 0; i < 4; ++i) {
        float4 v = *(const float4*)(xp + k0 + sc * 16 + i * 4);
        ssq += v.x * v.x + v.y * v.y + v.z * v.z + v.w * v.w;
      }
    }
    ssq += __shfl_xor(ssq, 1);
    ssq += __shfl_xor(ssq, 2);
    rnv = rsqrtf(ssq * (1.f / (float)Kd) + 1e-6f);
  }
  f32x4 acc[2][2] = {};
  for (int k0 = 0; k0 < Kd; k0 += 64) {
    __syncthreads();
    // stage A: 16 fp32 -> bf16 per thread
    #pragma unroll
    for (int i = 0; i < 4; ++i) {
      int k = sc * 16 + i * 4;
      float4 v;
      if (AMODE == 2) {
        float4 yf = *(const float4*)(A + (size_t)arow * 512 + k0 + k);
        float4 yb = *(const float4*)(A + (size_t)L_ * E_ + (size_t)(2047 - arow) * 512 + k0 + k);
        float4 z  = *(const float4*)(Aux1 + (size_t)arow * 1024 + k0 + k);
        v.x = (yf.x + yb.x) * siluf(z.x);
        v.y = (yf.y + yb.y) * siluf(z.y);
        v.z = (yf.z + yb.z) * siluf(z.z);
        v.w = (yf.w + yb.w) * siluf(z.w);
      } else {
        v = *(const float4*)(A + (size_t)arow * lda + k0 + k);
        if (AMODE == 1) {
          float4 w4 = *(const float4*)(Aux2 + k0 + k);
          v.x *= rnv * w4.x; v.y *= rnv * w4.y; v.z *= rnv * w4.z; v.w *= rnv * w4.w;
        }
      }
      uint2 p;
      p.x = (unsigned)f2b(v.x) | ((unsigned)f2b(v.y) << 16);
      p.y = (unsigned)f2b(v.z) | ((unsigned)f2b(v.w) << 16);
      unsigned off = (unsigned)(srow * 128 + k * 2) ^ swz;
      *(uint2*)((char*)Als + off) = p;
    }
    // stage B: 16 bf16 per thread (2 x 16B)
    {
      const unsigned short* bp = BT + (size_t)(n0 + srow) * Kd + k0 + sc * 8;
      #pragma unroll
      for (int i = 0; i < 2; ++i) {
        uint4 v = *(const uint4*)(bp + i * 32);
        unsigned off = (unsigned)(srow * 128 + (sc * 8 + i * 32) * 2) ^ swz;
        *(uint4*)((char*)Bls + off) = v;
      }
    }
    __syncthreads();
    #pragma unroll
    for (int ks = 0; ks < 64; ks += 32) {
      bf16x8 af[2], bfr[2];
      #pragma unroll
      for (int mi = 0; mi < 2; ++mi) {
        int row = wm * 32 + mi * 16 + (lane & 15);
        unsigned off = (unsigned)(row * 128 + (ks + (lane >> 4) * 8) * 2) ^ ((unsigned)((row & 7) << 4));
        af[mi] = *(const bf16x8*)((const char*)Als + off);
      }
      #pragma unroll
      for (int ni = 0; ni < 2; ++ni) {
        int row = wn * 32 + ni * 16 + (lane & 15);
        unsigned off = (unsigned)(row * 128 + (ks + (lane >> 4) * 8) * 2) ^ ((unsigned)((row & 7) << 4));
        bfr[ni] = *(const bf16x8*)((const char*)Bls + off);
      }
      #pragma unroll
      for (int mi = 0; mi < 2; ++mi)
        #pragma unroll
        for (int ni = 0; ni < 2; ++ni)
          acc[mi][ni] = __builtin_amdgcn_mfma_f32_16x16x32_bf16(af[mi], bfr[ni], acc[mi][ni], 0, 0, 0);
    }
  }
  #pragma unroll
  for (int mi = 0; mi < 2; ++mi) {
    #pragma unroll
    for (int ni = 0; ni < 2; ++ni) {
      int gm = m0 + wm * 32 + mi * 16 + (lane >> 4) * 4;
      int gn = n0 + wn * 32 + ni * 16 + (lane & 15);
      float bv = (MODE == 3 || MODE == 4 || MODE == 5) ? bias[gn] : 0.f;
      #pragma unroll
      for (int r = 0; r < 4; ++r) {
        float x = acc[mi][ni][r];
        if (MODE == 1) {
          if (gn < 512) {
            x += bias[gn];
            x = (x > 20.f) ? x : log1pf(__expf(x));
          }
        }
        if (MODE == 3 || MODE == 4 || MODE == 5) x += bv;
        size_t ci = (size_t)(gm + r) * ldc + gn;
        if (MODE == 5)      C[ci] = Aux1[ci] + x;
        else if (MODE == 2 || MODE == 4) C[ci] += x;
        else                C[ci] = x;
      }
    }
  }
}

// ---------------- depthwise causal conv (both directions) + silu, float4 ----------------
__global__ void conv_k(const float* __restrict__ XZ, const float* __restrict__ cw,
                       const float* __restrict__ cb, float* __restrict__ UC) {
  int idx = blockIdx.x * 256 + threadIdx.x;  // over L*E/4
  int e = (idx & 127) * 4;
  int l = idx >> 7;
  float4 w[4];
  #pragma unroll
  for (int k = 0; k < 4; ++k) w[k] = *(const float4*)(cw + k * 512 + e);
  float4 bb = *(const float4*)(cb + e);
  float4 af = bb, ab = bb;
  #pragma unroll
  for (int k = 0; k < 4; ++k) {
    int j = l - 3 + k;
    if (j >= 0) {
      float4 xf = *(const float4*)(XZ + (size_t)j * 1024 + e);
      float4 xb = *(const float4*)(XZ + (size_t)(2047 - j) * 1024 + e);
      af.x = fmaf(w[k].x, xf.x, af.x); af.y = fmaf(w[k].y, xf.y, af.y);
      af.z = fmaf(w[k].z, xf.z, af.z); af.w = fmaf(w[k].w, xf.w, af.w);
      ab.x = fmaf(w[k].x, xb.x, ab.x); ab.y = fmaf(w[k].y, xb.y, ab.y);
      ab.z = fmaf(w[k].z, xb.z, ab.z); ab.w = fmaf(w[k].w, xb.w, ab.w);
    }
  }
  float4 of, ob;
  of.x = siluf(af.x); of.y = siluf(af.y); of.z = siluf(af.z); of.w = siluf(af.w);
  ob.x = siluf(ab.x); ob.y = siluf(ab.y); ob.z = siluf(ab.z); ob.w = siluf(ab.w);
  *(float4*)(UC + (size_t)l * 512 + e) = of;
  *(float4*)(UC + (size_t)L_ * E_ + (size_t)l * 512 + e) = ob;
}

// ---------------- selective scan: thread=(dir,e), 16 states in regs ----------------
__global__ __launch_bounds__(256) void scan1_k(
    const float* __restrict__ PRDb, const float* __restrict__ UCb,
    const float* __restrict__ alog, float* __restrict__ SP, float* __restrict__ SH) {
  int b = blockIdx.x;
  int eg = b & 1, chunk = (b >> 1) & (CH - 1), dir = b >> 7;
  int e = eg * 256 + threadIdx.x;
  int l0 = chunk * CL;
  const float* prd = PRDb + (size_t)dir * L_ * 576;
  const float* ucp = UCb + (size_t)dir * L_ * E_;
  __shared__ float B_s[CL][16];
  for (int i = threadIdx.x; i < CL * 16; i += 256) {
    int l = i >> 4, n = i & 15;
    B_s[l][n] = prd[(size_t)(l0 + l) * 576 + 512 + n];
  }
  float A[16];
  #pragma unroll
  for (int n = 0; n < 16; n += 4) {
    float4 v = *(const float4*)&alog[(size_t)e * 16 + n];
    A[n] = -__expf(v.x); A[n+1] = -__expf(v.y); A[n+2] = -__expf(v.z); A[n+3] = -__expf(v.w);
  }
  float h[16];
  #pragma unroll
  for (int n = 0; n < 16; ++n) h[n] = 0.f;
  float sd = 0.f;
  __syncthreads();
  #pragma unroll
  for (int t = 0; t < CL; t += 8) {
    float d[8], u[8];
    #pragma unroll
    for (int j = 0; j < 8; ++j) {
      d[j] = prd[(size_t)(l0 + t + j) * 576 + e];
      u[j] = ucp[(size_t)(l0 + t + j) * E_ + e];
    }
    #pragma unroll
    for (int j = 0; j < 8; ++j) {
      float du = d[j] * u[j];
      sd += d[j];
      #pragma unroll
      for (int n = 0; n < 16; ++n)
        h[n] = fmaf(__expf(d[j] * A[n]), h[n], du * B_s[t + j][n]);
    }
  }
  size_t idx = ((size_t)(dir * CH + chunk) * 8192) + (size_t)e * 16;
  #pragma unroll
  for (int n = 0; n < 16; ++n) {
    SP[idx + n] = __expf(A[n] * sd);
    SH[idx + n] = h[n];
  }
}

__global__ void scan2_k(float* __restrict__ SP, const float* __restrict__ SH) {
  int idx = blockIdx.x * 256 + threadIdx.x;  // 2*8192
  if (idx >= 2 * E_ * 16) return;
  int dir = idx >> 13, en = idx & 8191;
  float c = 0.f;
  #pragma unroll
  for (int j = 0; j < CH; ++j) {
    size_t s = (size_t)(dir * CH + j) * 8192 + en;
    float p = SP[s], hh = SH[s];
    SP[s] = c;
    c = p * c + hh;
  }
}

__global__ __launch_bounds__(256) void scan3_k(
    const float* __restrict__ PRDb, const float* __restrict__ UCb,
    const float* __restrict__ alog, const float* __restrict__ dp,
    const float* __restrict__ CIN, float* __restrict__ Y2) {
  int b = blockIdx.x;
  int eg = b & 1, chunk = (b >> 1) & (CH - 1), dir = b >> 7;
  int e = eg * 256 + threadIdx.x;
  int l0 = chunk * CL;
  const float* prd = PRDb + (size_t)dir * L_ * 576;
  const float* ucp = UCb + (size_t)dir * L_ * E_;
  float* Y = Y2 + (size_t)dir * L_ * E_;
  __shared__ float B_s[CL][16], C_s[CL][16];
  for (int i = threadIdx.x; i < CL * 16; i += 256) {
    int l = i >> 4, n = i & 15;
    B_s[l][n] = prd[(size_t)(l0 + l) * 576 + 512 + n];
    C_s[l][n] = prd[(size_t)(l0 + l) * 576 + 528 + n];
  }
  float A[16];
  #pragma unroll
  for (int n = 0; n < 16; n += 4) {
    float4 v = *(const float4*)&alog[(size_t)e * 16 + n];
    A[n] = -__expf(v.x); A[n+1] = -__expf(v.y); A[n+2] = -__expf(v.z); A[n+3] = -__expf(v.w);
  }
  float D = dp[e];
  float h[16];
  {
    size_t idx = ((size_t)(dir * CH + chunk) * 8192) + (size_t)e * 16;
    #pragma unroll
    for (int n = 0; n < 16; n += 4) {
      float4 v = *(const float4*)&CIN[idx + n];
      h[n] = v.x; h[n+1] = v.y; h[n+2] = v.z; h[n+3] = v.w;
    }
  }
  __syncthreads();
  #pragma unroll
  for (int t = 0; t < CL; t += 8) {
    float d[8], u[8];
    #pragma unroll
    for (int j = 0; j < 8; ++j) {
      d[j] = prd[(size_t)(l0 + t + j) * 576 + e];
      u[j] = ucp[(size_t)(l0 + t + j) * E_ + e];
    }
    #pragma unroll
    for (int j = 0; j < 8; ++j) {
      float du = d[j] * u[j];
      float y0 = 0.f, y1 = 0.f, y2 = 0.f, y3 = 0.f;
      #pragma unroll
      for (int n = 0; n < 16; n += 4) {
        h[n]   = fmaf(__expf(d[j] * A[n]),   h[n],   du * B_s[t + j][n]);
        h[n+1] = fmaf(__expf(d[j] * A[n+1]), h[n+1], du * B_s[t + j][n+1]);
        h[n+2] = fmaf(__expf(d[j] * A[n+2]), h[n+2], du * B_s[t + j][n+2]);
        h[n+3] = fmaf(__expf(d[j] * A[n+3]), h[n+3], du * B_s[t + j][n+3]);
        y0 = fmaf(h[n],   C_s[t + j][n],   y0);
        y1 = fmaf(h[n+1], C_s[t + j][n+1], y1);
        y2 = fmaf(h[n+2], C_s[t + j][n+2], y2);
        y3 = fmaf(h[n+3], C_s[t + j][n+3], y3);
      }
      Y[(size_t)(l0 + t + j) * E_ + e] = (y0 + y1) + (y2 + y3) + u[j] * D;
    }
  }
}

// ---------------- cross-attention core (kw hoisted static-only; vw loads in-loop) --------
__global__ __launch_bounds__(256) void attn_k(
    const float* __restrict__ Q, const float* __restrict__ te,
    const float* __restrict__ kw, const float* __restrict__ vw, const float* __restrict__ vb,
    float* __restrict__ AO) {
  int lane = threadIdx.x & 63, h = threadIdx.x >> 6;
  int l0 = blockIdx.x * 4;  // grid 512
  const float* kp0 = kw + (size_t)lane * DM_ + h * 64;
  const float* vp0 = vw + h * 64 + lane;
  float vbv = vb[h * 64 + lane];
  float4 kf[16];
  #pragma unroll
  for (int i = 0; i < 16; ++i) kf[i] = *(const float4*)(kp0 + i * 4);
  for (int p = 0; p < 4; ++p) {
    int l = l0 + p;
    float q = Q[(size_t)l * DM_ + h * 64 + lane];
    float g = 0.f;
    #pragma unroll
    for (int d0 = 0; d0 < 64; d0 += 4) {
      float4 r = kf[d0 >> 2];
      g = fmaf(r.x, __shfl(q, d0 + 0), g);
      g = fmaf(r.y, __shfl(q, d0 + 1), g);
      g = fmaf(r.z, __shfl(q, d0 + 2), g);
      g = fmaf(r.w, __shfl(q, d0 + 3), g);
    }
    float tfv[8], pv[8];
    #pragma unroll
    for (int t = 0; t < 8; ++t) {
      tfv[t] = te[(size_t)t * L_ * 64 + (size_t)l * 64 + lane];
      pv[t] = tfv[t] * g;
    }
    #pragma unroll
    for (int t = 0; t < 8; ++t) {
      #pragma unroll
      for (int off = 1; off < 64; off <<= 1) pv[t] += __shfl_xor(pv[t], off);
    }
    float mx = pv[0];
    #pragma unroll
    for (int t = 1; t < 8; ++t) mx = fmaxf(mx, pv[t]);
    float s = 0.f;
    #pragma unroll
    for (int t = 0; t < 8; ++t) { pv[t] = __expf((pv[t] - mx) * 0.125f); s += pv[t]; }
    float inv = 1.f / s;
    float m = 0.f;
    #pragma unroll
    for (int t = 0; t < 8; ++t) m = fmaf(pv[t] * inv, tfv[t], m);
    float o = vbv;
    #pragma unroll 8
    for (int c = 0; c < 64; ++c)
      o = fmaf(__shfl(m, c), vp0[(size_t)c * DM_], o);
    AO[(size_t)l * DM_ + h * 64 + lane] = o;
  }
}

extern "C" void kernel_launch(void* const* d_in, const int* in_sizes, int n_in,
                              void* d_out, int out_size, void* d_ws, size_t ws_size,
                              hipStream_t stream) {
  (void)in_sizes; (void)n_in; (void)out_size; (void)ws_size;
  const float* x_in = (const float*)d_in[0];
  const float* te   = (const float*)d_in[1];
  const float* mnw  = (const float*)d_in[2];
  const float* ipw  = (const float*)d_in[3];
  const float* cw   = (const float*)d_in[4];
  const float* cb   = (const float*)d_in[5];
  const float* xpw  = (const float*)d_in[6];
  const float* dpw  = (const float*)d_in[7];
  const float* dpb  = (const float*)d_in[8];
  const float* alog = (const float*)d_in[9];
  const float* dprm = (const float*)d_in[10];
  const float* opw  = (const float*)d_in[11];
  const float* cnw  = (const float*)d_in[12];
  const float* qw   = (const float*)d_in[13];
  const float* qb   = (const float*)d_in[14];
  const float* kw   = (const float*)d_in[15];
  // d_in[16] = k_b: constant over tracks -> softmax-invariant, unused
  const float* vw   = (const float*)d_in[17];
  const float* vb   = (const float*)d_in[18];
  const float* ow   = (const float*)d_in[19];
  const float* ob   = (const float*)d_in[20];

  float* ws = (float*)d_ws;
  float* X   = ws + 0;          // 524288
  float* XZ  = ws + 524288;     // 2097152
  float* UC  = ws + 2621440;    // 2097152 (dir0, dir1)
  float* PRD = ws + 4718592;    // 2359296 = 2 x 2048 x 576
  float* Y2  = ws + 7077888;    // 2097152
  float* SP  = ws + 9175040;    // 1048576
  float* SH  = ws + 10223616;   // 1048576
  unsigned short* ipwT = (unsigned short*)(ws + 11272192);  // 524288 fl
  unsigned short* WXT  = (unsigned short*)(ws + 11796480);  // 589824 fl
  unsigned short* opwT = (unsigned short*)(ws + 12386304);  // 262144 fl
  unsigned short* qwT  = (unsigned short*)(ws + 12648448);  // 65536 fl
  unsigned short* owT  = (unsigned short*)(ws + 12713984);  // 65536 fl
  // end: 12779520 floats = 51.1 MB
  float* Qb = SP;  // alias SP (dead in CA phase)
  float* AO = SH;  // alias SH (dead in CA phase)

  wprep_k<<<6400, 256, 0, stream>>>(ipw, opw, qw, ow, xpw, dpw,
                                    ipwT, opwT, qwT, owT, WXT);

  hipMemcpyAsync(X, x_in, (size_t)L_ * DM_ * sizeof(float),
                 hipMemcpyDeviceToDevice, stream);

  for (int i = 0; i < 4; ++i) {
    mgemm_k<1,0><<<dim3(16, 32, 1), 256, 0, stream>>>(
        X, 256, 0, nullptr, mnw + i * 256, ipwT + (size_t)i * 1024 * 256, nullptr,
        XZ, 1024, 0, 256);
    conv_k<<<1024, 256, 0, stream>>>(XZ, cw + i * 4 * 512, cb + i * 512, UC);
    mgemm_k<0,1><<<dim3(9, 32, 2), 256, 0, stream>>>(
        UC, 512, 1048576, nullptr, nullptr, WXT + (size_t)i * 576 * 512, dpb + i * 512,
        PRD, 576, 1179648, 512);
    scan1_k<<<2 * CH * 2, 256, 0, stream>>>(PRD, UC, alog + (size_t)i * 512 * 16, SP, SH);
    scan2_k<<<64, 256, 0, stream>>>(SP, SH);
    scan3_k<<<2 * CH * 2, 256, 0, stream>>>(PRD, UC, alog + (size_t)i * 512 * 16,
                                            dprm + i * 512, SP, Y2);
    mgemm_k<2,2><<<dim3(4, 32, 1), 256, 0, stream>>>(
        Y2, 512, 0, XZ + 512, nullptr, opwT + (size_t)i * 256 * 512, nullptr,
        X, 256, 0, 512);

    if (i == 1 || i == 3) {
      int j = (i == 1) ? 0 : 1;
      mgemm_k<1,3><<<dim3(4, 32, 1), 256, 0, stream>>>(
          X, 256, 0, nullptr, cnw + j * 256, qwT + (size_t)j * 256 * 256, qb + j * 256,
          Qb, 256, 0, 256);
      attn_k<<<512, 256, 0, stream>>>(Qb, te, kw + (size_t)j * 64 * 256,
                                      vw + (size_t)j * 64 * 256, vb + j * 256, AO);
      if (i == 3) {
        // final op: residual + o-proj straight into d_out (saves the copy-out)
        mgemm_k<0,5><<<dim3(4, 32, 1), 256, 0, stream>>>(
            AO, 256, 0, X, nullptr, owT + (size_t)j * 256 * 256, ob + j * 256,
            (float*)d_out, 256, 0, 256);
      } else {
        mgemm_k<0,4><<<dim3(4, 32, 1), 256, 0, stream>>>(
            AO, 256, 0, nullptr, nullptr, owT + (size_t)j * 256 * 256, ob + j * 256,
            X, 256, 0, 256);
      }
    }
  }
}